// Round 14
// baseline (403.258 us; speedup 1.0000x reference)
//
#include <hip/hip_runtime.h>
#include <math.h>

#define NSLOPE 0.2f

typedef __attribute__((ext_vector_type(8))) short bf16x8;
typedef __attribute__((ext_vector_type(8))) unsigned short ushort8;
typedef __attribute__((ext_vector_type(4))) float f32x4;

static __device__ __forceinline__ float leaky(float e) {
    return e > 0.f ? e : NSLOPE * e;
}

static __device__ __forceinline__ float bfu(unsigned short u) {
    return __uint_as_float(((unsigned)u) << 16);
}

static __device__ __forceinline__ unsigned short f2bf_rne(float f) {
    unsigned b = __float_as_uint(f);
    unsigned r = b + 0x7fffu + ((b >> 16) & 1u);
    return (unsigned short)(r >> 16);
}

static __device__ __forceinline__ void split1(float f, unsigned short& hi,
                                              unsigned short& lo) {
    unsigned b = __float_as_uint(f);
    unsigned hb = b & 0xffff0000u;
    hi = (unsigned short)(hb >> 16);
    lo = (unsigned short)(__float_as_uint(f - __uint_as_float(hb)) >> 16);
}

// ---------------- CSR build ----------------

__global__ void k_count(const int* __restrict__ dst, int* __restrict__ cnt, int E) {
    int i = blockIdx.x * blockDim.x + threadIdx.x;
    if (i < E) atomicAdd(&cnt[dst[i]], 1);
}

__global__ void k_scan_local(const int* __restrict__ cnt, int* __restrict__ ptr,
                             int* __restrict__ bsum, int N) {
    __shared__ int sd[256];
    int t = threadIdx.x;
    int i0 = blockIdx.x * 1024 + t * 4;
    int v0 = (i0 + 0 < N) ? cnt[i0 + 0] : 0;
    int v1 = (i0 + 1 < N) ? cnt[i0 + 1] : 0;
    int v2 = (i0 + 2 < N) ? cnt[i0 + 2] : 0;
    int v3 = (i0 + 3 < N) ? cnt[i0 + 3] : 0;
    int ts = v0 + v1 + v2 + v3;
    sd[t] = ts;
    __syncthreads();
    for (int o = 1; o < 256; o <<= 1) {
        int add = (t >= o) ? sd[t - o] : 0;
        __syncthreads();
        sd[t] += add;
        __syncthreads();
    }
    int run = sd[t] - ts;
    if (i0 + 0 < N) ptr[i0 + 0] = run; run += v0;
    if (i0 + 1 < N) ptr[i0 + 1] = run; run += v1;
    if (i0 + 2 < N) ptr[i0 + 2] = run; run += v2;
    if (i0 + 3 < N) ptr[i0 + 3] = run;
    if (t == 255) bsum[blockIdx.x] = sd[255];
}

// per-block prefix of bsum; writes both ptr and the fill cursor fptr
__global__ void k_scan_add2(int* __restrict__ ptr, int* __restrict__ fptr,
                            const int* __restrict__ bsum, int N, int Et) {
    __shared__ int base;
    const int chunk = blockIdx.x >> 2;
    if (threadIdx.x == 0) {
        int s = 0;
        for (int b = 0; b < chunk; ++b) s += bsum[b];
        base = s;
    }
    __syncthreads();
    int i = blockIdx.x * 256 + threadIdx.x;
    if (i < N) {
        int v = ptr[i] + base;
        ptr[i] = v;
        fptr[i] = v;
    } else if (i == N) {
        ptr[N] = Et;
    }
}

__global__ void k_fillcsr(const int* __restrict__ ei, int* __restrict__ fptr,
                          int* __restrict__ srcs, int E, int Et) {
    int i = blockIdx.x * blockDim.x + threadIdx.x;
    if (i >= Et) return;
    int s, d;
    if (i < E) { s = ei[i]; d = ei[E + i]; }
    else       { s = d = i - E; }
    int pos = atomicAdd(&fptr[d], 1);
    srcs[pos] = s;
}

// ---------------- fused prep: cnt=1  ||  x split  ||  3x W transpose+split ---
__global__ __launch_bounds__(256) void k_prep(
    int* __restrict__ cnt, int N,
    const float* __restrict__ x, unsigned short* __restrict__ xhi,
    unsigned short* __restrict__ xlo, int n8,
    const float* __restrict__ W1, unsigned short* __restrict__ w1h, unsigned short* __restrict__ w1l,
    const float* __restrict__ W2, unsigned short* __restrict__ w2h, unsigned short* __restrict__ w2l,
    const float* __restrict__ W3, unsigned short* __restrict__ w3h, unsigned short* __restrict__ w3l,
    int nset, int nsplit) {
    __shared__ float tile[32][33];
    const int b = blockIdx.x;
    const int tid = threadIdx.x;
    if (b < nset) {
        int i = b * 256 + tid;
        if (i < N) cnt[i] = 1;
    } else if (b < nset + nsplit) {
        int i = (b - nset) * 256 + tid;
        if (i < n8) {
            const float4 v0 = *reinterpret_cast<const float4*>(&x[(size_t)i * 8]);
            const float4 v1 = *reinterpret_cast<const float4*>(&x[(size_t)i * 8 + 4]);
            const float f[8] = {v0.x, v0.y, v0.z, v0.w, v1.x, v1.y, v1.z, v1.w};
            ushort8 h, l;
#pragma unroll
            for (int j = 0; j < 8; ++j) {
                unsigned short hj, lj;
                split1(f[j], hj, lj);
                h[j] = hj; l[j] = lj;
            }
            *reinterpret_cast<ushort8*>(&xhi[(size_t)i * 8]) = h;
            *reinterpret_cast<ushort8*>(&xlo[(size_t)i * 8]) = l;
        }
    } else {
        int tb = b - nset - nsplit;     // 0..143
        const float* B; unsigned short *H, *L;
        int M, bx, by;
        if (tb < 64)       { B = W1; H = w1h; L = w1l; M = 256; bx = (tb & 7) * 32; by = (tb >> 3) * 32; }
        else if (tb < 128) { tb -= 64;  B = W2; H = w2h; L = w2l; M = 256; bx = (tb & 7) * 32; by = (tb >> 3) * 32; }
        else               { tb -= 128; B = W3; H = w3h; L = w3l; M = 64;  bx = (tb & 1) * 32; by = (tb >> 1) * 32; }
        constexpr int K = 256;
        const int tx = tid & 31, ty = tid >> 5;
        for (int r = ty; r < 32; r += 8) tile[r][tx] = B[(size_t)(by + r) * M + bx + tx];
        __syncthreads();
        for (int r = ty; r < 32; r += 8) {
            unsigned short h, l;
            split1(tile[tx][r], h, l);
            H[(size_t)(bx + r) * K + by + tx] = h;
            L[(size_t)(bx + r) * K + by + tx] = l;
        }
    }
}

// ---------------- wide GEMM, layers 1-2: BN=M=256, B direct from L2 ---------
// A staged in LDS (9.2 KB); W fragments read per-wave straight from global
// (W is 128 KB hi+lo, fully L2-resident). Same fragment bits + MFMA order as
// the staged version -> bit-identical output.
__global__ __launch_bounds__(256) void k_gemm2(const unsigned short* __restrict__ Ahi,
                                               const unsigned short* __restrict__ Alo,
                                               const unsigned short* __restrict__ Whi,
                                               const unsigned short* __restrict__ Wlo,
                                               const float* __restrict__ asrc,
                                               const float* __restrict__ adst,
                                               unsigned short* __restrict__ hb,
                                               float* __restrict__ als,
                                               float* __restrict__ ald,
                                               int N) {
    constexpr int K = 256;
    constexpr int M = 256;
    __shared__ unsigned short Ah[64][36], Al[64][36];
    const int tid = threadIdx.x;
    const int lane = tid & 63;
    const int wid = tid >> 6;
    const int row0 = blockIdx.x * 64;

    const int sr = tid >> 2;
    const int sk = (tid & 3) << 3;
    const int ga = row0 + sr;
    const size_t gaK = (size_t)ga * K;

    const int wc0 = wid * 64;
    const int fr = lane & 15;
    const int ko = (lane >> 4) * 8;

    // per-wave W row bases for its 4 column fragments
    const size_t wrow[4] = {
        (size_t)(wc0 + 0 * 16 + fr) * K + ko,
        (size_t)(wc0 + 1 * 16 + fr) * K + ko,
        (size_t)(wc0 + 2 * 16 + fr) * K + ko,
        (size_t)(wc0 + 3 * 16 + fr) * K + ko,
    };

    f32x4 acc[4][4];
#pragma unroll
    for (int i = 0; i < 4; ++i)
#pragma unroll
        for (int j = 0; j < 4; ++j) acc[i][j] = (f32x4){0.f, 0.f, 0.f, 0.f};

    for (int k0 = 0; k0 < K; k0 += 32) {
        ushort8 ah = {0,0,0,0,0,0,0,0}, al = {0,0,0,0,0,0,0,0};
        if (ga < N) {
            ah = *reinterpret_cast<const ushort8*>(&Ahi[gaK + k0 + sk]);
            al = *reinterpret_cast<const ushort8*>(&Alo[gaK + k0 + sk]);
        }
        *reinterpret_cast<ushort8*>(&Ah[sr][sk]) = ah;
        *reinterpret_cast<ushort8*>(&Al[sr][sk]) = al;
        __syncthreads();

        // issue all B loads first (L2-resident W) for MLP
        bf16x8 bh[4], bl[4];
#pragma unroll
        for (int j = 0; j < 4; ++j) {
            bh[j] = *reinterpret_cast<const bf16x8*>(&Whi[wrow[j] + k0]);
            bl[j] = *reinterpret_cast<const bf16x8*>(&Wlo[wrow[j] + k0]);
        }

        bf16x8 ahi[4], alo4[4];
#pragma unroll
        for (int i = 0; i < 4; ++i) {
            ahi[i]  = *reinterpret_cast<const bf16x8*>(&Ah[i * 16 + fr][ko]);
            alo4[i] = *reinterpret_cast<const bf16x8*>(&Al[i * 16 + fr][ko]);
        }
#pragma unroll
        for (int j = 0; j < 4; ++j) {
#pragma unroll
            for (int i = 0; i < 4; ++i) {
                acc[i][j] = __builtin_amdgcn_mfma_f32_16x16x32_bf16(ahi[i], bh[j], acc[i][j], 0, 0, 0);
                acc[i][j] = __builtin_amdgcn_mfma_f32_16x16x32_bf16(ahi[i], bl[j], acc[i][j], 0, 0, 0);
                acc[i][j] = __builtin_amdgcn_mfma_f32_16x16x32_bf16(alo4[i], bh[j], acc[i][j], 0, 0, 0);
            }
        }
        __syncthreads();
    }

    const int orow = (lane >> 4) * 4;
    const int ocol = lane & 15;

#pragma unroll
    for (int i = 0; i < 4; ++i) {
#pragma unroll
        for (int r = 0; r < 4; ++r) {
            const int row = row0 + i * 16 + orow + r;
            if (row < N) {
#pragma unroll
                for (int j = 0; j < 4; ++j) {
                    const int col = wc0 + j * 16 + ocol;
                    hb[(size_t)row * M + col] = f2bf_rne(acc[i][j][r]);
                }
            }
        }
    }

    const float as0 = asrc[wc0 + ocol],      as1 = asrc[wc0 + 16 + ocol];
    const float as2 = asrc[wc0 + 32 + ocol], as3 = asrc[wc0 + 48 + ocol];
    const float ad0 = adst[wc0 + ocol],      ad1 = adst[wc0 + 16 + ocol];
    const float ad2 = adst[wc0 + 32 + ocol], ad3 = adst[wc0 + 48 + ocol];
    const int headA = wc0 >> 5, headB = headA + 1;

#pragma unroll
    for (int i = 0; i < 4; ++i) {
#pragma unroll
        for (int r = 0; r < 4; ++r) {
            float psA = acc[i][0][r] * as0 + acc[i][1][r] * as1;
            float pdA = acc[i][0][r] * ad0 + acc[i][1][r] * ad1;
            float psB = acc[i][2][r] * as2 + acc[i][3][r] * as3;
            float pdB = acc[i][2][r] * ad2 + acc[i][3][r] * ad3;
#pragma unroll
            for (int o = 1; o < 16; o <<= 1) {
                psA += __shfl_xor(psA, o);
                pdA += __shfl_xor(pdA, o);
                psB += __shfl_xor(psB, o);
                pdB += __shfl_xor(pdB, o);
            }
            const int row = row0 + i * 16 + orow + r;
            if (ocol == 0 && row < N) {
                als[(size_t)row * 8 + headA] = psA;
                ald[(size_t)row * 8 + headA] = pdA;
                als[(size_t)row * 8 + headB] = psB;
                ald[(size_t)row * 8 + headB] = pdB;
            }
        }
    }
}

// ---------------- layer-3 GEMM (M=64) ----------------

template <int HN, int CN>
__global__ __launch_bounds__(256) void k_gemm_s(const unsigned short* __restrict__ Ahi,
                                                const unsigned short* __restrict__ Alo,
                                                const unsigned short* __restrict__ Whi,
                                                const unsigned short* __restrict__ Wlo,
                                                const float* __restrict__ asrc,
                                                const float* __restrict__ adst,
                                                unsigned short* __restrict__ hb,
                                                float* __restrict__ als,
                                                float* __restrict__ ald,
                                                int N) {
    constexpr int K = 256;
    constexpr int M = HN * CN;
    __shared__ unsigned short Ah[64][40], Al[64][40], Bh[64][40], Bl[64][40];
    const int tid = threadIdx.x;
    const int lane = tid & 63;
    const int wid = tid >> 6;
    const int row0 = blockIdx.x * 64;
    const int col0 = blockIdx.y * 64;

    const int sr = tid >> 2;
    const int sk = (tid & 3) << 3;
    const int ga = row0 + sr;
    const size_t gaK = (size_t)ga * K;
    const size_t gcK = (size_t)(col0 + sr) * K;

    const int wr = (wid >> 1) * 32;
    const int wc = (wid & 1) * 32;
    const int fr = lane & 15;
    const int ko = (lane >> 4) * 8;

    f32x4 acc[2][2];
#pragma unroll
    for (int i = 0; i < 2; ++i)
#pragma unroll
        for (int j = 0; j < 2; ++j) acc[i][j] = (f32x4){0.f, 0.f, 0.f, 0.f};

    for (int k0 = 0; k0 < K; k0 += 32) {
        ushort8 ah = {0,0,0,0,0,0,0,0}, al = {0,0,0,0,0,0,0,0};
        if (ga < N) {
            ah = *reinterpret_cast<const ushort8*>(&Ahi[gaK + k0 + sk]);
            al = *reinterpret_cast<const ushort8*>(&Alo[gaK + k0 + sk]);
        }
        const ushort8 bh = *reinterpret_cast<const ushort8*>(&Whi[gcK + k0 + sk]);
        const ushort8 bl = *reinterpret_cast<const ushort8*>(&Wlo[gcK + k0 + sk]);
        *reinterpret_cast<ushort8*>(&Ah[sr][sk]) = ah;
        *reinterpret_cast<ushort8*>(&Al[sr][sk]) = al;
        *reinterpret_cast<ushort8*>(&Bh[sr][sk]) = bh;
        *reinterpret_cast<ushort8*>(&Bl[sr][sk]) = bl;
        __syncthreads();

        bf16x8 ahi[2], alo[2], bhi[2], blo[2];
#pragma unroll
        for (int i = 0; i < 2; ++i) {
            ahi[i] = *reinterpret_cast<const bf16x8*>(&Ah[wr + i * 16 + fr][ko]);
            alo[i] = *reinterpret_cast<const bf16x8*>(&Al[wr + i * 16 + fr][ko]);
        }
#pragma unroll
        for (int j = 0; j < 2; ++j) {
            bhi[j] = *reinterpret_cast<const bf16x8*>(&Bh[wc + j * 16 + fr][ko]);
            blo[j] = *reinterpret_cast<const bf16x8*>(&Bl[wc + j * 16 + fr][ko]);
        }
#pragma unroll
        for (int i = 0; i < 2; ++i)
#pragma unroll
            for (int j = 0; j < 2; ++j) {
                acc[i][j] = __builtin_amdgcn_mfma_f32_16x16x32_bf16(ahi[i], bhi[j], acc[i][j], 0, 0, 0);
                acc[i][j] = __builtin_amdgcn_mfma_f32_16x16x32_bf16(ahi[i], blo[j], acc[i][j], 0, 0, 0);
                acc[i][j] = __builtin_amdgcn_mfma_f32_16x16x32_bf16(alo[i], bhi[j], acc[i][j], 0, 0, 0);
            }
        __syncthreads();
    }

    const int orow = (lane >> 4) * 4;
    const int ocol = lane & 15;

#pragma unroll
    for (int i = 0; i < 2; ++i) {
#pragma unroll
        for (int r = 0; r < 4; ++r) {
            const int row = row0 + wr + i * 16 + orow + r;
            if (row < N) {
#pragma unroll
                for (int j = 0; j < 2; ++j) {
                    const int col = col0 + wc + j * 16 + ocol;
                    hb[(size_t)row * M + col] = f2bf_rne(acc[i][j][r]);
                }
            }
        }
    }

    const int c0 = col0 + wc;
    const float as0 = asrc[c0 + ocol],      as1 = asrc[c0 + 16 + ocol];
    const float ad0 = adst[c0 + ocol],      ad1 = adst[c0 + 16 + ocol];

    {
        __shared__ float part[2][64][2];
#pragma unroll
        for (int i = 0; i < 2; ++i) {
#pragma unroll
            for (int r = 0; r < 4; ++r) {
                float ps = acc[i][0][r] * as0 + acc[i][1][r] * as1;
                float pd = acc[i][0][r] * ad0 + acc[i][1][r] * ad1;
#pragma unroll
                for (int o = 1; o < 16; o <<= 1) {
                    ps += __shfl_xor(ps, o);
                    pd += __shfl_xor(pd, o);
                }
                if (ocol == 0) {
                    const int lr = wr + i * 16 + orow + r;
                    part[wc >> 5][lr][0] = ps;
                    part[wc >> 5][lr][1] = pd;
                }
            }
        }
        __syncthreads();
        if (tid < 64) {
            const int row = row0 + tid;
            if (row < N) {
                als[row] = part[0][tid][0] + part[1][tid][0];
                ald[row] = part[0][tid][1] + part[1][tid][1];
            }
        }
    }
}

// ---------------- big-layer softmax + aggregate (round-12 verbatim) ---------
template <int HN, int CN, int VEC, int P, bool OSPLIT>
__global__ __launch_bounds__(256) void k_agg6(const unsigned short* __restrict__ hb,
                                              const float* __restrict__ als,
                                              const float* __restrict__ ald,
                                              const int* __restrict__ ptr,
                                              const int* __restrict__ srcs,
                                              const float* __restrict__ bias,
                                              unsigned short* __restrict__ ohi,
                                              unsigned short* __restrict__ olo,
                                              float* __restrict__ out,
                                              int N, int relu) {
    constexpr int HC = HN * CN;
    constexpr int SUBS = 64 / HN;
    constexpr int GB = (SUBS < 16) ? SUBS : 16;
    const int l = threadIdx.x & 63;
    const int n = blockIdx.x * 4 + (threadIdx.x >> 6);
    if (n >= N) return;
    const int beg = ptr[n], end = ptr[n + 1];
    const int hd_e = l % HN;
    const int sub = l / HN;
    const float aldv = ald[(unsigned)n * HN + hd_e];

    float p[P];
    int   sr[P];
    float ssum = 0.f;
#pragma unroll
    for (int b = 0; b < P; ++b) {
        const int j = beg + b * SUBS + sub;
        float pv = 0.f; int s = 0;
        if (j < end) {
            s = srcs[j];
            pv = __expf(leaky(als[(unsigned)s * HN + hd_e] + aldv));
        }
        sr[b] = s; p[b] = pv; ssum += pv;
    }
    for (int j = beg + P * SUBS + sub; j < end; j += SUBS) {
        ssum += __expf(leaky(als[(unsigned)srcs[j] * HN + hd_e] + aldv));
    }
#pragma unroll
    for (int o = HN; o < 64; o <<= 1) ssum += __shfl_xor(ssum, o);
    const float inv = 1.f / (ssum + 1e-16f);

    const int ch = l * VEC;
    const int hl = ch / CN;
    float acc[VEC];
#pragma unroll
    for (int v = 0; v < VEC; ++v) acc[v] = 0.f;

#pragma unroll
    for (int b = 0; b < P; ++b) {
        const int j0 = beg + b * SUBS;
        if (j0 >= end) break;
        const float am = p[b] * inv;
#pragma unroll
        for (int cb = 0; cb < SUBS / GB; ++cb) {
            if (j0 + cb * GB >= end) break;
            float av[GB];
            if constexpr (VEC == 4) {
                ushort4 hv[GB];
#pragma unroll
                for (int c = 0; c < GB; ++c) {
                    const int ce = cb * GB + c;
                    const int s = __shfl(sr[b], ce * HN);
                    av[c] = __shfl(am, ce * HN + hl);
                    hv[c] = *reinterpret_cast<const ushort4*>(&hb[(unsigned)s * HC + ch]);
                }
#pragma unroll
                for (int c = 0; c < GB; ++c) {
                    acc[0] += av[c] * bfu(hv[c].x);
                    acc[1] += av[c] * bfu(hv[c].y);
                    acc[2] += av[c] * bfu(hv[c].z);
                    acc[3] += av[c] * bfu(hv[c].w);
                }
            } else {
                unsigned short hv[GB];
#pragma unroll
                for (int c = 0; c < GB; ++c) {
                    const int ce = cb * GB + c;
                    const int s = __shfl(sr[b], ce * HN);
                    av[c] = __shfl(am, ce * HN + hl);
                    hv[c] = hb[(unsigned)s * HC + ch];
                }
#pragma unroll
                for (int c = 0; c < GB; ++c) acc[0] += av[c] * bfu(hv[c]);
            }
        }
    }
    for (int j0 = beg + P * SUBS; j0 < end; j0 += SUBS) {
        const int j = j0 + sub;
        int sm = 0; float am = 0.f;
        if (j < end) {
            sm = srcs[j];
            am = __expf(leaky(als[(unsigned)sm * HN + hd_e] + aldv)) * inv;
        }
#pragma unroll
        for (int cb = 0; cb < SUBS / GB; ++cb) {
            if (j0 + cb * GB >= end) break;
            float av[GB];
            if constexpr (VEC == 4) {
                ushort4 hv[GB];
#pragma unroll
                for (int c = 0; c < GB; ++c) {
                    const int ce = cb * GB + c;
                    const int s = __shfl(sm, ce * HN);
                    av[c] = __shfl(am, ce * HN + hl);
                    hv[c] = *reinterpret_cast<const ushort4*>(&hb[(unsigned)s * HC + ch]);
                }
#pragma unroll
                for (int c = 0; c < GB; ++c) {
                    acc[0] += av[c] * bfu(hv[c].x);
                    acc[1] += av[c] * bfu(hv[c].y);
                    acc[2] += av[c] * bfu(hv[c].z);
                    acc[3] += av[c] * bfu(hv[c].w);
                }
            } else {
                unsigned short hv[GB];
#pragma unroll
                for (int c = 0; c < GB; ++c) {
                    const int ce = cb * GB + c;
                    const int s = __shfl(sm, ce * HN);
                    av[c] = __shfl(am, ce * HN + hl);
                    hv[c] = hb[(unsigned)s * HC + ch];
                }
#pragma unroll
                for (int c = 0; c < GB; ++c) acc[0] += av[c] * bfu(hv[c]);
            }
        }
    }

#pragma unroll
    for (int v = 0; v < VEC; ++v) {
        float o = acc[v] + bias[ch + v];
        if (relu) o = fmaxf(o, 0.f);
        acc[v] = o;
    }
    if constexpr (OSPLIT) {
        ushort4 ho, lo4;
        unsigned short h0, l0;
        split1(acc[0], h0, l0); ho.x = h0; lo4.x = l0;
        split1(acc[1], h0, l0); ho.y = h0; lo4.y = l0;
        split1(acc[2], h0, l0); ho.z = h0; lo4.z = l0;
        split1(acc[3], h0, l0); ho.w = h0; lo4.w = l0;
        *reinterpret_cast<ushort4*>(&ohi[(unsigned)n * HC + ch]) = ho;
        *reinterpret_cast<ushort4*>(&olo[(unsigned)n * HC + ch]) = lo4;
    } else if constexpr (VEC == 4) {
        float4 vout;
        vout.x = acc[0]; vout.y = acc[1]; vout.z = acc[2]; vout.w = acc[3];
        *reinterpret_cast<float4*>(&out[(unsigned)n * HC + ch]) = vout;
    } else {
        out[(unsigned)n * HC + ch] = acc[0];
    }
}

// ---------------- layer-3 aggregate (round-12 verbatim, passing) ------------
template <int P>
__global__ __launch_bounds__(256) void k_agg7(const unsigned short* __restrict__ hb,
                                              const float* __restrict__ als,
                                              const float* __restrict__ ald,
                                              const int* __restrict__ ptr,
                                              const int* __restrict__ srcs,
                                              const float* __restrict__ bias,
                                              float* __restrict__ out,
                                              int N) {
    constexpr int HC = 64;
    const int l = threadIdx.x & 63;
    const int n = blockIdx.x * 4 + (threadIdx.x >> 6);
    if (n >= N) return;
    const int beg = ptr[n], end = ptr[n + 1];
    const float aldv = ald[n];

    float p[P];
    int   sr[P];
    float ssum = 0.f;
#pragma unroll
    for (int b = 0; b < P; ++b) {
        const int j = beg + b * 64 + l;
        float pv = 0.f; int s = 0;
        if (j < end) { s = srcs[j]; pv = __expf(leaky(als[s] + aldv)); }
        sr[b] = s; p[b] = pv; ssum += pv;
    }
    for (int j = beg + P * 64 + l; j < end; j += 64)
        ssum += __expf(leaky(als[srcs[j]] + aldv));
#pragma unroll
    for (int o = 1; o < 64; o <<= 1) ssum += __shfl_xor(ssum, o);
    const float inv = 1.f / (ssum + 1e-16f);

    const int grp = l >> 4;
    const int lch = (l & 15) * 4;
    float acc[4] = {0.f, 0.f, 0.f, 0.f};

#pragma unroll
    for (int b = 0; b < P; ++b) {
        const int j0 = beg + b * 64;
        if (j0 >= end) break;
        const float am = p[b] * inv;
        const int ned = min(64, end - j0);
        const int nblk = (ned + 15) >> 4;
        for (int cb = 0; cb < nblk; ++cb) {
            const int e0 = cb * 16 + grp;
            const float a0 = __shfl(am, e0),       a1 = __shfl(am, e0 + 4);
            const float a2 = __shfl(am, e0 + 8),   a3 = __shfl(am, e0 + 12);
            const int   s0 = __shfl(sr[b], e0),      s1 = __shfl(sr[b], e0 + 4);
            const int   s2 = __shfl(sr[b], e0 + 8),  s3 = __shfl(sr[b], e0 + 12);
            const ushort4 h0 = *reinterpret_cast<const ushort4*>(&hb[(unsigned)s0 * HC + lch]);
            const ushort4 h1 = *reinterpret_cast<const ushort4*>(&hb[(unsigned)s1 * HC + lch]);
            const ushort4 h2 = *reinterpret_cast<const ushort4*>(&hb[(unsigned)s2 * HC + lch]);
            const ushort4 h3 = *reinterpret_cast<const ushort4*>(&hb[(unsigned)s3 * HC + lch]);
            acc[0] += a0 * bfu(h0.x) + a1 * bfu(h1.x) + a2 * bfu(h2.x) + a3 * bfu(h3.x);
            acc[1] += a0 * bfu(h0.y) + a1 * bfu(h1.y) + a2 * bfu(h2.y) + a3 * bfu(h3.y);
            acc[2] += a0 * bfu(h0.z) + a1 * bfu(h1.z) + a2 * bfu(h2.z) + a3 * bfu(h3.z);
            acc[3] += a0 * bfu(h0.w) + a1 * bfu(h1.w) + a2 * bfu(h2.w) + a3 * bfu(h3.w);
        }
    }
    for (int j0 = beg + P * 64; j0 < end; j0 += 64) {
        const int j = j0 + l;
        int sm = 0; float am = 0.f;
        if (j < end) { sm = srcs[j]; am = __expf(leaky(als[sm] + aldv)) * inv; }
        const int ned = min(64, end - j0);
        const int nblk = (ned + 15) >> 4;
        for (int cb = 0; cb < nblk; ++cb) {
            const int e0 = cb * 16 + grp;
            const float a0 = __shfl(am, e0),       a1 = __shfl(am, e0 + 4);
            const float a2 = __shfl(am, e0 + 8),   a3 = __shfl(am, e0 + 12);
            const int   s0 = __shfl(sm, e0),       s1 = __shfl(sm, e0 + 4);
            const int   s2 = __shfl(sm, e0 + 8),   s3 = __shfl(sm, e0 + 12);
            const ushort4 h0 = *reinterpret_cast<const ushort4*>(&hb[(unsigned)s0 * HC + lch]);
            const ushort4 h1 = *reinterpret_cast<const ushort4*>(&hb[(unsigned)s1 * HC + lch]);
            const ushort4 h2 = *reinterpret_cast<const ushort4*>(&hb[(unsigned)s2 * HC + lch]);
            const ushort4 h3 = *reinterpret_cast<const ushort4*>(&hb[(unsigned)s3 * HC + lch]);
            acc[0] += a0 * bfu(h0.x) + a1 * bfu(h1.x) + a2 * bfu(h2.x) + a3 * bfu(h3.x);
            acc[1] += a0 * bfu(h0.y) + a1 * bfu(h1.y) + a2 * bfu(h2.y) + a3 * bfu(h3.y);
            acc[2] += a0 * bfu(h0.z) + a1 * bfu(h1.z) + a2 * bfu(h2.z) + a3 * bfu(h3.z);
            acc[3] += a0 * bfu(h0.w) + a1 * bfu(h1.w) + a2 * bfu(h2.w) + a3 * bfu(h3.w);
        }
    }

#pragma unroll
    for (int o = 16; o < 64; o <<= 1) {
#pragma unroll
        for (int v = 0; v < 4; ++v) acc[v] += __shfl_xor(acc[v], o);
    }

    if (l < 16) {
        float4 vout;
        vout.x = acc[0] + bias[lch + 0];
        vout.y = acc[1] + bias[lch + 1];
        vout.z = acc[2] + bias[lch + 2];
        vout.w = acc[3] + bias[lch + 3];
        *reinterpret_cast<float4*>(&out[(size_t)n * HC + lch]) = vout;
    }
}

// ---------------- launch ----------------

extern "C" void kernel_launch(void* const* d_in, const int* in_sizes, int n_in,
                              void* d_out, int out_size, void* d_ws, size_t ws_size,
                              hipStream_t stream) {
    const float* x   = (const float*)d_in[0];
    const int*   ei  = (const int*)d_in[1];
    const float* W1  = (const float*)d_in[2];
    const float* as1 = (const float*)d_in[3];
    const float* ad1 = (const float*)d_in[4];
    const float* b1  = (const float*)d_in[5];
    const float* W2  = (const float*)d_in[6];
    const float* as2 = (const float*)d_in[7];
    const float* ad2 = (const float*)d_in[8];
    const float* b2  = (const float*)d_in[9];
    const float* W3  = (const float*)d_in[10];
    const float* as3 = (const float*)d_in[11];
    const float* ad3 = (const float*)d_in[12];
    const float* b3  = (const float*)d_in[13];

    const int F  = 256;
    const int N  = in_sizes[0] / F;     // 50000
    const int E  = in_sizes[1] / 2;     // 800000
    const int Et = E + N;

    char* w = (char*)d_ws;
    auto alloc = [&](size_t bytes) {
        char* p = w;
        w += (bytes + 255) & ~(size_t)255;
        return p;
    };
    unsigned short* S0hi = (unsigned short*)alloc((size_t)N * F * 2);
    unsigned short* S0lo = (unsigned short*)alloc((size_t)N * F * 2);
    unsigned short* S1hi = (unsigned short*)alloc((size_t)N * F * 2);
    unsigned short* S1lo = (unsigned short*)alloc((size_t)N * F * 2);
    unsigned short* hB   = (unsigned short*)alloc((size_t)N * F * 2);
    unsigned short* Wt1hi = (unsigned short*)alloc((size_t)256 * 256 * 2);
    unsigned short* Wt1lo = (unsigned short*)alloc((size_t)256 * 256 * 2);
    unsigned short* Wt2hi = (unsigned short*)alloc((size_t)256 * 256 * 2);
    unsigned short* Wt2lo = (unsigned short*)alloc((size_t)256 * 256 * 2);
    unsigned short* Wt3hi = (unsigned short*)alloc((size_t)64 * 256 * 2);
    unsigned short* Wt3lo = (unsigned short*)alloc((size_t)64 * 256 * 2);
    float* als  = (float*)alloc((size_t)N * 8 * 4);
    float* ald  = (float*)alloc((size_t)N * 8 * 4);
    int*   cnt  = (int*)alloc((size_t)N * 4);
    int*   ptr  = (int*)alloc((size_t)(N + 1) * 4);
    int*   fptr = (int*)alloc((size_t)(N + 1) * 4);
    int*   srcs = (int*)alloc((size_t)Et * 4);
    int*   bsum = (int*)alloc(4096);

    const int n8 = N * F / 8;
    const int nset = (N + 255) / 256;
    const int nsplit = (n8 + 255) / 256;
    const int nprep = nset + nsplit + 64 + 64 + 16;

    hipLaunchKernelGGL(k_prep, dim3(nprep), dim3(256), 0, stream,
                       cnt, N, x, S0hi, S0lo, n8,
                       W1, Wt1hi, Wt1lo, W2, Wt2hi, Wt2lo, W3, Wt3hi, Wt3lo,
                       nset, nsplit);

    const int nb = (N + 1023) / 1024;
    hipLaunchKernelGGL(k_count,     dim3((E + 255) / 256),  dim3(256), 0, stream, ei + E, cnt, E);
    hipLaunchKernelGGL(k_scan_local,dim3(nb),               dim3(256), 0, stream, cnt, ptr, bsum, N);
    hipLaunchKernelGGL(k_scan_add2, dim3((N + 256) / 256),  dim3(256), 0, stream, ptr, fptr, bsum, N, Et);
    hipLaunchKernelGGL(k_fillcsr,   dim3((Et + 255) / 256), dim3(256), 0, stream, ei, fptr, srcs, E, Et);

    const dim3 gN4((N + 3) / 4);
    const int gx = (N + 63) / 64;

    // ---- layer 1 ----
    hipLaunchKernelGGL(k_gemm2, dim3(gx), dim3(256), 0, stream,
                       S0hi, S0lo, Wt1hi, Wt1lo, as1, ad1, hB, als, ald, N);
    hipLaunchKernelGGL((k_agg6<8, 32, 4, 8, true>), gN4, dim3(256), 0, stream,
                       hB, als, ald, ptr, srcs, b1, S1hi, S1lo, nullptr, N, 1);
    // ---- layer 2 ----
    hipLaunchKernelGGL(k_gemm2, dim3(gx), dim3(256), 0, stream,
                       S1hi, S1lo, Wt2hi, Wt2lo, as2, ad2, hB, als, ald, N);
    hipLaunchKernelGGL((k_agg6<8, 32, 4, 8, true>), gN4, dim3(256), 0, stream,
                       hB, als, ald, ptr, srcs, b2, S0hi, S0lo, nullptr, N, 1);
    // ---- layer 3 ----
    hipLaunchKernelGGL((k_gemm_s<1, 64>), dim3(gx, 1), dim3(256), 0, stream,
                       S0hi, S0lo, Wt3hi, Wt3lo, as3, ad3, hB, als, ald, N);
    hipLaunchKernelGGL((k_agg7<2>), gN4, dim3(256), 0, stream,
                       hB, als, ald, ptr, srcs, b3, (float*)d_out, N);
}

// Round 15
// 385.445 us; speedup vs baseline: 1.0462x; 1.0462x over previous
//
#include <hip/hip_runtime.h>
#include <math.h>

#define NSLOPE 0.2f

typedef __attribute__((ext_vector_type(8))) short bf16x8;
typedef __attribute__((ext_vector_type(8))) unsigned short ushort8;
typedef __attribute__((ext_vector_type(4))) float f32x4;

static __device__ __forceinline__ float leaky(float e) {
    return e > 0.f ? e : NSLOPE * e;
}

static __device__ __forceinline__ float bfu(unsigned short u) {
    return __uint_as_float(((unsigned)u) << 16);
}

static __device__ __forceinline__ unsigned short f2bf_rne(float f) {
    unsigned b = __float_as_uint(f);
    unsigned r = b + 0x7fffu + ((b >> 16) & 1u);
    return (unsigned short)(r >> 16);
}

static __device__ __forceinline__ void split1(float f, unsigned short& hi,
                                              unsigned short& lo) {
    unsigned b = __float_as_uint(f);
    unsigned hb = b & 0xffff0000u;
    hi = (unsigned short)(hb >> 16);
    lo = (unsigned short)(__float_as_uint(f - __uint_as_float(hb)) >> 16);
}

// ---------------- CSR build ----------------
// cnt is zeroed via hipMemsetAsync; counting runs inside k_prep; the
// self-loop (+1 per node) is folded into k_scan_local.

__global__ void k_scan_local(const int* __restrict__ cnt, int* __restrict__ ptr,
                             int* __restrict__ bsum, int N) {
    __shared__ int sd[256];
    int t = threadIdx.x;
    int i0 = blockIdx.x * 1024 + t * 4;
    int v0 = (i0 + 0 < N) ? cnt[i0 + 0] + 1 : 0;
    int v1 = (i0 + 1 < N) ? cnt[i0 + 1] + 1 : 0;
    int v2 = (i0 + 2 < N) ? cnt[i0 + 2] + 1 : 0;
    int v3 = (i0 + 3 < N) ? cnt[i0 + 3] + 1 : 0;
    int ts = v0 + v1 + v2 + v3;
    sd[t] = ts;
    __syncthreads();
    for (int o = 1; o < 256; o <<= 1) {
        int add = (t >= o) ? sd[t - o] : 0;
        __syncthreads();
        sd[t] += add;
        __syncthreads();
    }
    int run = sd[t] - ts;
    if (i0 + 0 < N) ptr[i0 + 0] = run; run += v0;
    if (i0 + 1 < N) ptr[i0 + 1] = run; run += v1;
    if (i0 + 2 < N) ptr[i0 + 2] = run; run += v2;
    if (i0 + 3 < N) ptr[i0 + 3] = run;
    if (t == 255) bsum[blockIdx.x] = sd[255];
}

// per-block prefix of bsum; writes both ptr and the fill cursor fptr
__global__ void k_scan_add2(int* __restrict__ ptr, int* __restrict__ fptr,
                            const int* __restrict__ bsum, int N, int Et) {
    __shared__ int base;
    const int chunk = blockIdx.x >> 2;
    if (threadIdx.x == 0) {
        int s = 0;
        for (int b = 0; b < chunk; ++b) s += bsum[b];
        base = s;
    }
    __syncthreads();
    int i = blockIdx.x * 256 + threadIdx.x;
    if (i < N) {
        int v = ptr[i] + base;
        ptr[i] = v;
        fptr[i] = v;
    } else if (i == N) {
        ptr[N] = Et;
    }
}

__global__ void k_fillcsr(const int* __restrict__ ei, int* __restrict__ fptr,
                          int* __restrict__ srcs, int E, int Et) {
    int i = blockIdx.x * blockDim.x + threadIdx.x;
    if (i >= Et) return;
    int s, d;
    if (i < E) { s = ei[i]; d = ei[E + i]; }
    else       { s = d = i - E; }
    int pos = atomicAdd(&fptr[d], 1);
    srcs[pos] = s;
}

// ---------------- fused prep: edge count || x split || 3x W transpose+split -
__global__ __launch_bounds__(256) void k_prep(
    const int* __restrict__ ei_dst, int* __restrict__ cnt, int E, int N,
    const float* __restrict__ x, unsigned short* __restrict__ xhi,
    unsigned short* __restrict__ xlo, int n8,
    const float* __restrict__ W1, unsigned short* __restrict__ w1h, unsigned short* __restrict__ w1l,
    const float* __restrict__ W2, unsigned short* __restrict__ w2h, unsigned short* __restrict__ w2l,
    const float* __restrict__ W3, unsigned short* __restrict__ w3h, unsigned short* __restrict__ w3l,
    int ncnt, int nsplit) {
    __shared__ float tile[32][33];
    const int b = blockIdx.x;
    const int tid = threadIdx.x;
    if (b < ncnt) {
        int i = b * 256 + tid;
        if (i < E) atomicAdd(&cnt[ei_dst[i]], 1);
    } else if (b < ncnt + nsplit) {
        int i = (b - ncnt) * 256 + tid;
        if (i < n8) {
            const float4 v0 = *reinterpret_cast<const float4*>(&x[(size_t)i * 8]);
            const float4 v1 = *reinterpret_cast<const float4*>(&x[(size_t)i * 8 + 4]);
            const float f[8] = {v0.x, v0.y, v0.z, v0.w, v1.x, v1.y, v1.z, v1.w};
            ushort8 h, l;
#pragma unroll
            for (int j = 0; j < 8; ++j) {
                unsigned short hj, lj;
                split1(f[j], hj, lj);
                h[j] = hj; l[j] = lj;
            }
            *reinterpret_cast<ushort8*>(&xhi[(size_t)i * 8]) = h;
            *reinterpret_cast<ushort8*>(&xlo[(size_t)i * 8]) = l;
        }
    } else {
        int tb = b - ncnt - nsplit;     // 0..143
        const float* B; unsigned short *H, *L;
        int M, bx, by;
        if (tb < 64)       { B = W1; H = w1h; L = w1l; M = 256; bx = (tb & 7) * 32; by = (tb >> 3) * 32; }
        else if (tb < 128) { tb -= 64;  B = W2; H = w2h; L = w2l; M = 256; bx = (tb & 7) * 32; by = (tb >> 3) * 32; }
        else               { tb -= 128; B = W3; H = w3h; L = w3l; M = 64;  bx = (tb & 1) * 32; by = (tb >> 1) * 32; }
        constexpr int K = 256;
        const int tx = tid & 31, ty = tid >> 5;
        for (int r = ty; r < 32; r += 8) tile[r][tx] = B[(size_t)(by + r) * M + bx + tx];
        __syncthreads();
        for (int r = ty; r < 32; r += 8) {
            unsigned short h, l;
            split1(tile[tx][r], h, l);
            H[(size_t)(bx + r) * K + by + tx] = h;
            L[(size_t)(bx + r) * K + by + tx] = l;
        }
    }
}

// ---------------- wide GEMM for layers 1-2 (round-12 verbatim) --------------
__global__ __launch_bounds__(256) void k_gemm2(const unsigned short* __restrict__ Ahi,
                                               const unsigned short* __restrict__ Alo,
                                               const unsigned short* __restrict__ Whi,
                                               const unsigned short* __restrict__ Wlo,
                                               const float* __restrict__ asrc,
                                               const float* __restrict__ adst,
                                               unsigned short* __restrict__ hb,
                                               float* __restrict__ als,
                                               float* __restrict__ ald,
                                               int N) {
    constexpr int K = 256;
    constexpr int M = 256;
    __shared__ unsigned short Ah[64][36], Al[64][36];
    __shared__ unsigned short Bh[256][36], Bl[256][36];
    const int tid = threadIdx.x;
    const int lane = tid & 63;
    const int wid = tid >> 6;
    const int row0 = blockIdx.x * 64;

    const int sr = tid >> 2;
    const int sk = (tid & 3) << 3;
    const int ga = row0 + sr;
    const size_t gaK = (size_t)ga * K;

    const int wc0 = wid * 64;
    const int fr = lane & 15;
    const int ko = (lane >> 4) * 8;

    f32x4 acc[4][4];
#pragma unroll
    for (int i = 0; i < 4; ++i)
#pragma unroll
        for (int j = 0; j < 4; ++j) acc[i][j] = (f32x4){0.f, 0.f, 0.f, 0.f};

    for (int k0 = 0; k0 < K; k0 += 32) {
        ushort8 ah = {0,0,0,0,0,0,0,0}, al = {0,0,0,0,0,0,0,0};
        if (ga < N) {
            ah = *reinterpret_cast<const ushort8*>(&Ahi[gaK + k0 + sk]);
            al = *reinterpret_cast<const ushort8*>(&Alo[gaK + k0 + sk]);
        }
        *reinterpret_cast<ushort8*>(&Ah[sr][sk]) = ah;
        *reinterpret_cast<ushort8*>(&Al[sr][sk]) = al;
#pragma unroll
        for (int p = 0; p < 4; ++p) {
            const int m = sr + 64 * p;
            const size_t gm = (size_t)m * K + k0 + sk;
            *reinterpret_cast<ushort8*>(&Bh[m][sk]) =
                *reinterpret_cast<const ushort8*>(&Whi[gm]);
            *reinterpret_cast<ushort8*>(&Bl[m][sk]) =
                *reinterpret_cast<const ushort8*>(&Wlo[gm]);
        }
        __syncthreads();

        bf16x8 ahi[4], alo4[4];
#pragma unroll
        for (int i = 0; i < 4; ++i) {
            ahi[i]  = *reinterpret_cast<const bf16x8*>(&Ah[i * 16 + fr][ko]);
            alo4[i] = *reinterpret_cast<const bf16x8*>(&Al[i * 16 + fr][ko]);
        }
#pragma unroll
        for (int j = 0; j < 4; ++j) {
            const bf16x8 bh = *reinterpret_cast<const bf16x8*>(&Bh[wc0 + j * 16 + fr][ko]);
            const bf16x8 bl = *reinterpret_cast<const bf16x8*>(&Bl[wc0 + j * 16 + fr][ko]);
#pragma unroll
            for (int i = 0; i < 4; ++i) {
                acc[i][j] = __builtin_amdgcn_mfma_f32_16x16x32_bf16(ahi[i], bh, acc[i][j], 0, 0, 0);
                acc[i][j] = __builtin_amdgcn_mfma_f32_16x16x32_bf16(ahi[i], bl, acc[i][j], 0, 0, 0);
                acc[i][j] = __builtin_amdgcn_mfma_f32_16x16x32_bf16(alo4[i], bh, acc[i][j], 0, 0, 0);
            }
        }
        __syncthreads();
    }

    const int orow = (lane >> 4) * 4;
    const int ocol = lane & 15;

#pragma unroll
    for (int i = 0; i < 4; ++i) {
#pragma unroll
        for (int r = 0; r < 4; ++r) {
            const int row = row0 + i * 16 + orow + r;
            if (row < N) {
#pragma unroll
                for (int j = 0; j < 4; ++j) {
                    const int col = wc0 + j * 16 + ocol;
                    hb[(size_t)row * M + col] = f2bf_rne(acc[i][j][r]);
                }
            }
        }
    }

    const float as0 = asrc[wc0 + ocol],      as1 = asrc[wc0 + 16 + ocol];
    const float as2 = asrc[wc0 + 32 + ocol], as3 = asrc[wc0 + 48 + ocol];
    const float ad0 = adst[wc0 + ocol],      ad1 = adst[wc0 + 16 + ocol];
    const float ad2 = adst[wc0 + 32 + ocol], ad3 = adst[wc0 + 48 + ocol];
    const int headA = wc0 >> 5, headB = headA + 1;

#pragma unroll
    for (int i = 0; i < 4; ++i) {
#pragma unroll
        for (int r = 0; r < 4; ++r) {
            float psA = acc[i][0][r] * as0 + acc[i][1][r] * as1;
            float pdA = acc[i][0][r] * ad0 + acc[i][1][r] * ad1;
            float psB = acc[i][2][r] * as2 + acc[i][3][r] * as3;
            float pdB = acc[i][2][r] * ad2 + acc[i][3][r] * ad3;
#pragma unroll
            for (int o = 1; o < 16; o <<= 1) {
                psA += __shfl_xor(psA, o);
                pdA += __shfl_xor(pdA, o);
                psB += __shfl_xor(psB, o);
                pdB += __shfl_xor(pdB, o);
            }
            const int row = row0 + i * 16 + orow + r;
            if (ocol == 0 && row < N) {
                als[(size_t)row * 8 + headA] = psA;
                ald[(size_t)row * 8 + headA] = pdA;
                als[(size_t)row * 8 + headB] = psB;
                ald[(size_t)row * 8 + headB] = pdB;
            }
        }
    }
}

// ---------------- layer-3 GEMM (M=64, round-12 verbatim) --------------------

template <int HN, int CN>
__global__ __launch_bounds__(256) void k_gemm_s(const unsigned short* __restrict__ Ahi,
                                                const unsigned short* __restrict__ Alo,
                                                const unsigned short* __restrict__ Whi,
                                                const unsigned short* __restrict__ Wlo,
                                                const float* __restrict__ asrc,
                                                const float* __restrict__ adst,
                                                unsigned short* __restrict__ hb,
                                                float* __restrict__ als,
                                                float* __restrict__ ald,
                                                int N) {
    constexpr int K = 256;
    constexpr int M = HN * CN;
    __shared__ unsigned short Ah[64][40], Al[64][40], Bh[64][40], Bl[64][40];
    const int tid = threadIdx.x;
    const int lane = tid & 63;
    const int wid = tid >> 6;
    const int row0 = blockIdx.x * 64;
    const int col0 = blockIdx.y * 64;

    const int sr = tid >> 2;
    const int sk = (tid & 3) << 3;
    const int ga = row0 + sr;
    const size_t gaK = (size_t)ga * K;
    const size_t gcK = (size_t)(col0 + sr) * K;

    const int wr = (wid >> 1) * 32;
    const int wc = (wid & 1) * 32;
    const int fr = lane & 15;
    const int ko = (lane >> 4) * 8;

    f32x4 acc[2][2];
#pragma unroll
    for (int i = 0; i < 2; ++i)
#pragma unroll
        for (int j = 0; j < 2; ++j) acc[i][j] = (f32x4){0.f, 0.f, 0.f, 0.f};

    for (int k0 = 0; k0 < K; k0 += 32) {
        ushort8 ah = {0,0,0,0,0,0,0,0}, al = {0,0,0,0,0,0,0,0};
        if (ga < N) {
            ah = *reinterpret_cast<const ushort8*>(&Ahi[gaK + k0 + sk]);
            al = *reinterpret_cast<const ushort8*>(&Alo[gaK + k0 + sk]);
        }
        const ushort8 bh = *reinterpret_cast<const ushort8*>(&Whi[gcK + k0 + sk]);
        const ushort8 bl = *reinterpret_cast<const ushort8*>(&Wlo[gcK + k0 + sk]);
        *reinterpret_cast<ushort8*>(&Ah[sr][sk]) = ah;
        *reinterpret_cast<ushort8*>(&Al[sr][sk]) = al;
        *reinterpret_cast<ushort8*>(&Bh[sr][sk]) = bh;
        *reinterpret_cast<ushort8*>(&Bl[sr][sk]) = bl;
        __syncthreads();

        bf16x8 ahi[2], alo[2], bhi[2], blo[2];
#pragma unroll
        for (int i = 0; i < 2; ++i) {
            ahi[i] = *reinterpret_cast<const bf16x8*>(&Ah[wr + i * 16 + fr][ko]);
            alo[i] = *reinterpret_cast<const bf16x8*>(&Al[wr + i * 16 + fr][ko]);
        }
#pragma unroll
        for (int j = 0; j < 2; ++j) {
            bhi[j] = *reinterpret_cast<const bf16x8*>(&Bh[wc + j * 16 + fr][ko]);
            blo[j] = *reinterpret_cast<const bf16x8*>(&Bl[wc + j * 16 + fr][ko]);
        }
#pragma unroll
        for (int i = 0; i < 2; ++i)
#pragma unroll
            for (int j = 0; j < 2; ++j) {
                acc[i][j] = __builtin_amdgcn_mfma_f32_16x16x32_bf16(ahi[i], bhi[j], acc[i][j], 0, 0, 0);
                acc[i][j] = __builtin_amdgcn_mfma_f32_16x16x32_bf16(ahi[i], blo[j], acc[i][j], 0, 0, 0);
                acc[i][j] = __builtin_amdgcn_mfma_f32_16x16x32_bf16(alo[i], bhi[j], acc[i][j], 0, 0, 0);
            }
        __syncthreads();
    }

    const int orow = (lane >> 4) * 4;
    const int ocol = lane & 15;

#pragma unroll
    for (int i = 0; i < 2; ++i) {
#pragma unroll
        for (int r = 0; r < 4; ++r) {
            const int row = row0 + wr + i * 16 + orow + r;
            if (row < N) {
#pragma unroll
                for (int j = 0; j < 2; ++j) {
                    const int col = col0 + wc + j * 16 + ocol;
                    hb[(size_t)row * M + col] = f2bf_rne(acc[i][j][r]);
                }
            }
        }
    }

    const int c0 = col0 + wc;
    const float as0 = asrc[c0 + ocol],      as1 = asrc[c0 + 16 + ocol];
    const float ad0 = adst[c0 + ocol],      ad1 = adst[c0 + 16 + ocol];

    {
        __shared__ float part[2][64][2];
#pragma unroll
        for (int i = 0; i < 2; ++i) {
#pragma unroll
            for (int r = 0; r < 4; ++r) {
                float ps = acc[i][0][r] * as0 + acc[i][1][r] * as1;
                float pd = acc[i][0][r] * ad0 + acc[i][1][r] * ad1;
#pragma unroll
                for (int o = 1; o < 16; o <<= 1) {
                    ps += __shfl_xor(ps, o);
                    pd += __shfl_xor(pd, o);
                }
                if (ocol == 0) {
                    const int lr = wr + i * 16 + orow + r;
                    part[wc >> 5][lr][0] = ps;
                    part[wc >> 5][lr][1] = pd;
                }
            }
        }
        __syncthreads();
        if (tid < 64) {
            const int row = row0 + tid;
            if (row < N) {
                als[row] = part[0][tid][0] + part[1][tid][0];
                ald[row] = part[0][tid][1] + part[1][tid][1];
            }
        }
    }
}

// ---------------- big-layer softmax + aggregate (round-12 verbatim) ---------
template <int HN, int CN, int VEC, int P, bool OSPLIT>
__global__ __launch_bounds__(256) void k_agg6(const unsigned short* __restrict__ hb,
                                              const float* __restrict__ als,
                                              const float* __restrict__ ald,
                                              const int* __restrict__ ptr,
                                              const int* __restrict__ srcs,
                                              const float* __restrict__ bias,
                                              unsigned short* __restrict__ ohi,
                                              unsigned short* __restrict__ olo,
                                              float* __restrict__ out,
                                              int N, int relu) {
    constexpr int HC = HN * CN;
    constexpr int SUBS = 64 / HN;
    constexpr int GB = (SUBS < 16) ? SUBS : 16;
    const int l = threadIdx.x & 63;
    const int n = blockIdx.x * 4 + (threadIdx.x >> 6);
    if (n >= N) return;
    const int beg = ptr[n], end = ptr[n + 1];
    const int hd_e = l % HN;
    const int sub = l / HN;
    const float aldv = ald[(unsigned)n * HN + hd_e];

    float p[P];
    int   sr[P];
    float ssum = 0.f;
#pragma unroll
    for (int b = 0; b < P; ++b) {
        const int j = beg + b * SUBS + sub;
        float pv = 0.f; int s = 0;
        if (j < end) {
            s = srcs[j];
            pv = __expf(leaky(als[(unsigned)s * HN + hd_e] + aldv));
        }
        sr[b] = s; p[b] = pv; ssum += pv;
    }
    for (int j = beg + P * SUBS + sub; j < end; j += SUBS) {
        ssum += __expf(leaky(als[(unsigned)srcs[j] * HN + hd_e] + aldv));
    }
#pragma unroll
    for (int o = HN; o < 64; o <<= 1) ssum += __shfl_xor(ssum, o);
    const float inv = 1.f / (ssum + 1e-16f);

    const int ch = l * VEC;
    const int hl = ch / CN;
    float acc[VEC];
#pragma unroll
    for (int v = 0; v < VEC; ++v) acc[v] = 0.f;

#pragma unroll
    for (int b = 0; b < P; ++b) {
        const int j0 = beg + b * SUBS;
        if (j0 >= end) break;
        const float am = p[b] * inv;
#pragma unroll
        for (int cb = 0; cb < SUBS / GB; ++cb) {
            if (j0 + cb * GB >= end) break;
            float av[GB];
            if constexpr (VEC == 4) {
                ushort4 hv[GB];
#pragma unroll
                for (int c = 0; c < GB; ++c) {
                    const int ce = cb * GB + c;
                    const int s = __shfl(sr[b], ce * HN);
                    av[c] = __shfl(am, ce * HN + hl);
                    hv[c] = *reinterpret_cast<const ushort4*>(&hb[(unsigned)s * HC + ch]);
                }
#pragma unroll
                for (int c = 0; c < GB; ++c) {
                    acc[0] += av[c] * bfu(hv[c].x);
                    acc[1] += av[c] * bfu(hv[c].y);
                    acc[2] += av[c] * bfu(hv[c].z);
                    acc[3] += av[c] * bfu(hv[c].w);
                }
            } else {
                unsigned short hv[GB];
#pragma unroll
                for (int c = 0; c < GB; ++c) {
                    const int ce = cb * GB + c;
                    const int s = __shfl(sr[b], ce * HN);
                    av[c] = __shfl(am, ce * HN + hl);
                    hv[c] = hb[(unsigned)s * HC + ch];
                }
#pragma unroll
                for (int c = 0; c < GB; ++c) acc[0] += av[c] * bfu(hv[c]);
            }
        }
    }
    for (int j0 = beg + P * SUBS; j0 < end; j0 += SUBS) {
        const int j = j0 + sub;
        int sm = 0; float am = 0.f;
        if (j < end) {
            sm = srcs[j];
            am = __expf(leaky(als[(unsigned)sm * HN + hd_e] + aldv)) * inv;
        }
#pragma unroll
        for (int cb = 0; cb < SUBS / GB; ++cb) {
            if (j0 + cb * GB >= end) break;
            float av[GB];
            if constexpr (VEC == 4) {
                ushort4 hv[GB];
#pragma unroll
                for (int c = 0; c < GB; ++c) {
                    const int ce = cb * GB + c;
                    const int s = __shfl(sm, ce * HN);
                    av[c] = __shfl(am, ce * HN + hl);
                    hv[c] = *reinterpret_cast<const ushort4*>(&hb[(unsigned)s * HC + ch]);
                }
#pragma unroll
                for (int c = 0; c < GB; ++c) {
                    acc[0] += av[c] * bfu(hv[c].x);
                    acc[1] += av[c] * bfu(hv[c].y);
                    acc[2] += av[c] * bfu(hv[c].z);
                    acc[3] += av[c] * bfu(hv[c].w);
                }
            } else {
                unsigned short hv[GB];
#pragma unroll
                for (int c = 0; c < GB; ++c) {
                    const int ce = cb * GB + c;
                    const int s = __shfl(sm, ce * HN);
                    av[c] = __shfl(am, ce * HN + hl);
                    hv[c] = hb[(unsigned)s * HC + ch];
                }
#pragma unroll
                for (int c = 0; c < GB; ++c) acc[0] += av[c] * bfu(hv[c]);
            }
        }
    }

#pragma unroll
    for (int v = 0; v < VEC; ++v) {
        float o = acc[v] + bias[ch + v];
        if (relu) o = fmaxf(o, 0.f);
        acc[v] = o;
    }
    if constexpr (OSPLIT) {
        ushort4 ho, lo4;
        unsigned short h0, l0;
        split1(acc[0], h0, l0); ho.x = h0; lo4.x = l0;
        split1(acc[1], h0, l0); ho.y = h0; lo4.y = l0;
        split1(acc[2], h0, l0); ho.z = h0; lo4.z = l0;
        split1(acc[3], h0, l0); ho.w = h0; lo4.w = l0;
        *reinterpret_cast<ushort4*>(&ohi[(unsigned)n * HC + ch]) = ho;
        *reinterpret_cast<ushort4*>(&olo[(unsigned)n * HC + ch]) = lo4;
    } else if constexpr (VEC == 4) {
        float4 vout;
        vout.x = acc[0]; vout.y = acc[1]; vout.z = acc[2]; vout.w = acc[3];
        *reinterpret_cast<float4*>(&out[(unsigned)n * HC + ch]) = vout;
    } else {
        out[(unsigned)n * HC + ch] = acc[0];
    }
}

// ---------------- layer-3 aggregate (round-12 verbatim, passing) ------------
template <int P>
__global__ __launch_bounds__(256) void k_agg7(const unsigned short* __restrict__ hb,
                                              const float* __restrict__ als,
                                              const float* __restrict__ ald,
                                              const int* __restrict__ ptr,
                                              const int* __restrict__ srcs,
                                              const float* __restrict__ bias,
                                              float* __restrict__ out,
                                              int N) {
    constexpr int HC = 64;
    const int l = threadIdx.x & 63;
    const int n = blockIdx.x * 4 + (threadIdx.x >> 6);
    if (n >= N) return;
    const int beg = ptr[n], end = ptr[n + 1];
    const float aldv = ald[n];

    float p[P];
    int   sr[P];
    float ssum = 0.f;
#pragma unroll
    for (int b = 0; b < P; ++b) {
        const int j = beg + b * 64 + l;
        float pv = 0.f; int s = 0;
        if (j < end) { s = srcs[j]; pv = __expf(leaky(als[s] + aldv)); }
        sr[b] = s; p[b] = pv; ssum += pv;
    }
    for (int j = beg + P * 64 + l; j < end; j += 64)
        ssum += __expf(leaky(als[srcs[j]] + aldv));
#pragma unroll
    for (int o = 1; o < 64; o <<= 1) ssum += __shfl_xor(ssum, o);
    const float inv = 1.f / (ssum + 1e-16f);

    const int grp = l >> 4;
    const int lch = (l & 15) * 4;
    float acc[4] = {0.f, 0.f, 0.f, 0.f};

#pragma unroll
    for (int b = 0; b < P; ++b) {
        const int j0 = beg + b * 64;
        if (j0 >= end) break;
        const float am = p[b] * inv;
        const int ned = min(64, end - j0);
        const int nblk = (ned + 15) >> 4;
        for (int cb = 0; cb < nblk; ++cb) {
            const int e0 = cb * 16 + grp;
            const float a0 = __shfl(am, e0),       a1 = __shfl(am, e0 + 4);
            const float a2 = __shfl(am, e0 + 8),   a3 = __shfl(am, e0 + 12);
            const int   s0 = __shfl(sr[b], e0),      s1 = __shfl(sr[b], e0 + 4);
            const int   s2 = __shfl(sr[b], e0 + 8),  s3 = __shfl(sr[b], e0 + 12);
            const ushort4 h0 = *reinterpret_cast<const ushort4*>(&hb[(unsigned)s0 * HC + lch]);
            const ushort4 h1 = *reinterpret_cast<const ushort4*>(&hb[(unsigned)s1 * HC + lch]);
            const ushort4 h2 = *reinterpret_cast<const ushort4*>(&hb[(unsigned)s2 * HC + lch]);
            const ushort4 h3 = *reinterpret_cast<const ushort4*>(&hb[(unsigned)s3 * HC + lch]);
            acc[0] += a0 * bfu(h0.x) + a1 * bfu(h1.x) + a2 * bfu(h2.x) + a3 * bfu(h3.x);
            acc[1] += a0 * bfu(h0.y) + a1 * bfu(h1.y) + a2 * bfu(h2.y) + a3 * bfu(h3.y);
            acc[2] += a0 * bfu(h0.z) + a1 * bfu(h1.z) + a2 * bfu(h2.z) + a3 * bfu(h3.z);
            acc[3] += a0 * bfu(h0.w) + a1 * bfu(h1.w) + a2 * bfu(h2.w) + a3 * bfu(h3.w);
        }
    }
    for (int j0 = beg + P * 64; j0 < end; j0 += 64) {
        const int j = j0 + l;
        int sm = 0; float am = 0.f;
        if (j < end) { sm = srcs[j]; am = __expf(leaky(als[sm] + aldv)) * inv; }
        const int ned = min(64, end - j0);
        const int nblk = (ned + 15) >> 4;
        for (int cb = 0; cb < nblk; ++cb) {
            const int e0 = cb * 16 + grp;
            const float a0 = __shfl(am, e0),       a1 = __shfl(am, e0 + 4);
            const float a2 = __shfl(am, e0 + 8),   a3 = __shfl(am, e0 + 12);
            const int   s0 = __shfl(sm, e0),       s1 = __shfl(sm, e0 + 4);
            const int   s2 = __shfl(sm, e0 + 8),   s3 = __shfl(sm, e0 + 12);
            const ushort4 h0 = *reinterpret_cast<const ushort4*>(&hb[(unsigned)s0 * HC + lch]);
            const ushort4 h1 = *reinterpret_cast<const ushort4*>(&hb[(unsigned)s1 * HC + lch]);
            const ushort4 h2 = *reinterpret_cast<const ushort4*>(&hb[(unsigned)s2 * HC + lch]);
            const ushort4 h3 = *reinterpret_cast<const ushort4*>(&hb[(unsigned)s3 * HC + lch]);
            acc[0] += a0 * bfu(h0.x) + a1 * bfu(h1.x) + a2 * bfu(h2.x) + a3 * bfu(h3.x);
            acc[1] += a0 * bfu(h0.y) + a1 * bfu(h1.y) + a2 * bfu(h2.y) + a3 * bfu(h3.y);
            acc[2] += a0 * bfu(h0.z) + a1 * bfu(h1.z) + a2 * bfu(h2.z) + a3 * bfu(h3.z);
            acc[3] += a0 * bfu(h0.w) + a1 * bfu(h1.w) + a2 * bfu(h2.w) + a3 * bfu(h3.w);
        }
    }

#pragma unroll
    for (int o = 16; o < 64; o <<= 1) {
#pragma unroll
        for (int v = 0; v < 4; ++v) acc[v] += __shfl_xor(acc[v], o);
    }

    if (l < 16) {
        float4 vout;
        vout.x = acc[0] + bias[lch + 0];
        vout.y = acc[1] + bias[lch + 1];
        vout.z = acc[2] + bias[lch + 2];
        vout.w = acc[3] + bias[lch + 3];
        *reinterpret_cast<float4*>(&out[(size_t)n * HC + lch]) = vout;
    }
}

// ---------------- launch ----------------

extern "C" void kernel_launch(void* const* d_in, const int* in_sizes, int n_in,
                              void* d_out, int out_size, void* d_ws, size_t ws_size,
                              hipStream_t stream) {
    const float* x   = (const float*)d_in[0];
    const int*   ei  = (const int*)d_in[1];
    const float* W1  = (const float*)d_in[2];
    const float* as1 = (const float*)d_in[3];
    const float* ad1 = (const float*)d_in[4];
    const float* b1  = (const float*)d_in[5];
    const float* W2  = (const float*)d_in[6];
    const float* as2 = (const float*)d_in[7];
    const float* ad2 = (const float*)d_in[8];
    const float* b2  = (const float*)d_in[9];
    const float* W3  = (const float*)d_in[10];
    const float* as3 = (const float*)d_in[11];
    const float* ad3 = (const float*)d_in[12];
    const float* b3  = (const float*)d_in[13];

    const int F  = 256;
    const int N  = in_sizes[0] / F;     // 50000
    const int E  = in_sizes[1] / 2;     // 800000
    const int Et = E + N;

    char* w = (char*)d_ws;
    auto alloc = [&](size_t bytes) {
        char* p = w;
        w += (bytes + 255) & ~(size_t)255;
        return p;
    };
    unsigned short* S0hi = (unsigned short*)alloc((size_t)N * F * 2);
    unsigned short* S0lo = (unsigned short*)alloc((size_t)N * F * 2);
    unsigned short* S1hi = (unsigned short*)alloc((size_t)N * F * 2);
    unsigned short* S1lo = (unsigned short*)alloc((size_t)N * F * 2);
    unsigned short* hB   = (unsigned short*)alloc((size_t)N * F * 2);
    unsigned short* Wt1hi = (unsigned short*)alloc((size_t)256 * 256 * 2);
    unsigned short* Wt1lo = (unsigned short*)alloc((size_t)256 * 256 * 2);
    unsigned short* Wt2hi = (unsigned short*)alloc((size_t)256 * 256 * 2);
    unsigned short* Wt2lo = (unsigned short*)alloc((size_t)256 * 256 * 2);
    unsigned short* Wt3hi = (unsigned short*)alloc((size_t)64 * 256 * 2);
    unsigned short* Wt3lo = (unsigned short*)alloc((size_t)64 * 256 * 2);
    float* als  = (float*)alloc((size_t)N * 8 * 4);
    float* ald  = (float*)alloc((size_t)N * 8 * 4);
    int*   cnt  = (int*)alloc((size_t)N * 4);
    int*   ptr  = (int*)alloc((size_t)(N + 1) * 4);
    int*   fptr = (int*)alloc((size_t)(N + 1) * 4);
    int*   srcs = (int*)alloc((size_t)Et * 4);
    int*   bsum = (int*)alloc(4096);

    const int n8 = N * F / 8;
    const int ncnt = (E + 255) / 256;
    const int nsplit = (n8 + 255) / 256;
    const int nprep = ncnt + nsplit + 64 + 64 + 16;

    // zero cnt, then prep (edge count || x split || W transposes)
    hipMemsetAsync(cnt, 0, (size_t)N * 4, stream);
    hipLaunchKernelGGL(k_prep, dim3(nprep), dim3(256), 0, stream,
                       ei + E, cnt, E, N, x, S0hi, S0lo, n8,
                       W1, Wt1hi, Wt1lo, W2, Wt2hi, Wt2lo, W3, Wt3hi, Wt3lo,
                       ncnt, nsplit);

    const int nb = (N + 1023) / 1024;
    hipLaunchKernelGGL(k_scan_local,dim3(nb),               dim3(256), 0, stream, cnt, ptr, bsum, N);
    hipLaunchKernelGGL(k_scan_add2, dim3((N + 256) / 256),  dim3(256), 0, stream, ptr, fptr, bsum, N, Et);
    hipLaunchKernelGGL(k_fillcsr,   dim3((Et + 255) / 256), dim3(256), 0, stream, ei, fptr, srcs, E, Et);

    const dim3 gN4((N + 3) / 4);
    const int gx = (N + 63) / 64;

    // ---- layer 1 ----
    hipLaunchKernelGGL(k_gemm2, dim3(gx), dim3(256), 0, stream,
                       S0hi, S0lo, Wt1hi, Wt1lo, as1, ad1, hB, als, ald, N);
    hipLaunchKernelGGL((k_agg6<8, 32, 4, 8, true>), gN4, dim3(256), 0, stream,
                       hB, als, ald, ptr, srcs, b1, S1hi, S1lo, nullptr, N, 1);
    // ---- layer 2 ----
    hipLaunchKernelGGL(k_gemm2, dim3(gx), dim3(256), 0, stream,
                       S1hi, S1lo, Wt2hi, Wt2lo, as2, ad2, hB, als, ald, N);
    hipLaunchKernelGGL((k_agg6<8, 32, 4, 8, true>), gN4, dim3(256), 0, stream,
                       hB, als, ald, ptr, srcs, b2, S0hi, S0lo, nullptr, N, 1);
    // ---- layer 3 ----
    hipLaunchKernelGGL((k_gemm_s<1, 64>), dim3(gx, 1), dim3(256), 0, stream,
                       S0hi, S0lo, Wt3hi, Wt3lo, as3, ad3, hB, als, ald, N);
    hipLaunchKernelGGL((k_agg7<2>), gN4, dim3(256), 0, stream,
                       hB, als, ald, ptr, srcs, b3, (float*)d_out, N);
}

// Round 16
// 367.575 us; speedup vs baseline: 1.0971x; 1.0486x over previous
//
#include <hip/hip_runtime.h>
#include <math.h>

#define NSLOPE 0.2f

typedef __attribute__((ext_vector_type(8))) short bf16x8;
typedef __attribute__((ext_vector_type(8))) unsigned short ushort8;
typedef __attribute__((ext_vector_type(4))) float f32x4;

static __device__ __forceinline__ float leaky(float e) {
    return e > 0.f ? e : NSLOPE * e;
}

static __device__ __forceinline__ float bfu(unsigned short u) {
    return __uint_as_float(((unsigned)u) << 16);
}

static __device__ __forceinline__ unsigned short f2bf_rne(float f) {
    unsigned b = __float_as_uint(f);
    unsigned r = b + 0x7fffu + ((b >> 16) & 1u);
    return (unsigned short)(r >> 16);
}

static __device__ __forceinline__ void split1(float f, unsigned short& hi,
                                              unsigned short& lo) {
    unsigned b = __float_as_uint(f);
    unsigned hb = b & 0xffff0000u;
    hi = (unsigned short)(hb >> 16);
    lo = (unsigned short)(__float_as_uint(f - __uint_as_float(hb)) >> 16);
}

// ---------------- CSR build (r12-timed structure) ----------------

__global__ void k_count(const int* __restrict__ dst, int* __restrict__ cnt, int E) {
    int i = blockIdx.x * blockDim.x + threadIdx.x;
    if (i < E) atomicAdd(&cnt[dst[i]], 1);
}

// self-loop +1 folded in
__global__ void k_scan_local(const int* __restrict__ cnt, int* __restrict__ ptr,
                             int* __restrict__ bsum, int N) {
    __shared__ int sd[256];
    int t = threadIdx.x;
    int i0 = blockIdx.x * 1024 + t * 4;
    int v0 = (i0 + 0 < N) ? cnt[i0 + 0] + 1 : 0;
    int v1 = (i0 + 1 < N) ? cnt[i0 + 1] + 1 : 0;
    int v2 = (i0 + 2 < N) ? cnt[i0 + 2] + 1 : 0;
    int v3 = (i0 + 3 < N) ? cnt[i0 + 3] + 1 : 0;
    int ts = v0 + v1 + v2 + v3;
    sd[t] = ts;
    __syncthreads();
    for (int o = 1; o < 256; o <<= 1) {
        int add = (t >= o) ? sd[t - o] : 0;
        __syncthreads();
        sd[t] += add;
        __syncthreads();
    }
    int run = sd[t] - ts;
    if (i0 + 0 < N) ptr[i0 + 0] = run; run += v0;
    if (i0 + 1 < N) ptr[i0 + 1] = run; run += v1;
    if (i0 + 2 < N) ptr[i0 + 2] = run; run += v2;
    if (i0 + 3 < N) ptr[i0 + 3] = run;
    if (t == 255) bsum[blockIdx.x] = sd[255];
}

__global__ void k_scan_add2(int* __restrict__ ptr, int* __restrict__ fptr,
                            const int* __restrict__ bsum, int N, int Et) {
    __shared__ int base;
    const int chunk = blockIdx.x >> 2;
    if (threadIdx.x == 0) {
        int s = 0;
        for (int b = 0; b < chunk; ++b) s += bsum[b];
        base = s;
    }
    __syncthreads();
    int i = blockIdx.x * 256 + threadIdx.x;
    if (i < N) {
        int v = ptr[i] + base;
        ptr[i] = v;
        fptr[i] = v;
    } else if (i == N) {
        ptr[N] = Et;
    }
}

__global__ void k_fillcsr(const int* __restrict__ ei, int* __restrict__ fptr,
                          int* __restrict__ srcs, int E, int Et) {
    int i = blockIdx.x * blockDim.x + threadIdx.x;
    if (i >= Et) return;
    int s, d;
    if (i < E) { s = ei[i]; d = ei[E + i]; }
    else       { s = d = i - E; }
    int pos = atomicAdd(&fptr[d], 1);
    srcs[pos] = s;
}

// ---------------- fused prep: x -> bf16 (RNE)  ||  3x W transpose+split -----
__global__ __launch_bounds__(256) void k_prep(
    const float* __restrict__ x, unsigned short* __restrict__ xb, int n8,
    const float* __restrict__ W1, unsigned short* __restrict__ w1h, unsigned short* __restrict__ w1l,
    const float* __restrict__ W2, unsigned short* __restrict__ w2h, unsigned short* __restrict__ w2l,
    const float* __restrict__ W3, unsigned short* __restrict__ w3h, unsigned short* __restrict__ w3l,
    int nsplit) {
    __shared__ float tile[32][33];
    const int b = blockIdx.x;
    const int tid = threadIdx.x;
    if (b < nsplit) {
        int i = b * 256 + tid;
        if (i < n8) {
            const float4 v0 = *reinterpret_cast<const float4*>(&x[(size_t)i * 8]);
            const float4 v1 = *reinterpret_cast<const float4*>(&x[(size_t)i * 8 + 4]);
            const float f[8] = {v0.x, v0.y, v0.z, v0.w, v1.x, v1.y, v1.z, v1.w};
            ushort8 h;
#pragma unroll
            for (int j = 0; j < 8; ++j) h[j] = f2bf_rne(f[j]);
            *reinterpret_cast<ushort8*>(&xb[(size_t)i * 8]) = h;
        }
    } else {
        int tb = b - nsplit;            // 0..143
        const float* B; unsigned short *H, *L;
        int M, bx, by;
        if (tb < 64)       { B = W1; H = w1h; L = w1l; M = 256; bx = (tb & 7) * 32; by = (tb >> 3) * 32; }
        else if (tb < 128) { tb -= 64;  B = W2; H = w2h; L = w2l; M = 256; bx = (tb & 7) * 32; by = (tb >> 3) * 32; }
        else               { tb -= 128; B = W3; H = w3h; L = w3l; M = 64;  bx = (tb & 1) * 32; by = (tb >> 1) * 32; }
        constexpr int K = 256;
        const int tx = tid & 31, ty = tid >> 5;
        for (int r = ty; r < 32; r += 8) tile[r][tx] = B[(size_t)(by + r) * M + bx + tx];
        __syncthreads();
        for (int r = ty; r < 32; r += 8) {
            unsigned short h, l;
            split1(tile[tx][r], h, l);
            H[(size_t)(bx + r) * K + by + tx] = h;
            L[(size_t)(bx + r) * K + by + tx] = l;
        }
    }
}

// ---------------- wide GEMM, layers 1-2: A bf16, W split, 2 MFMA/frag -------
__global__ __launch_bounds__(256) void k_gemm2(const unsigned short* __restrict__ Ab,
                                               const unsigned short* __restrict__ Whi,
                                               const unsigned short* __restrict__ Wlo,
                                               const float* __restrict__ asrc,
                                               const float* __restrict__ adst,
                                               unsigned short* __restrict__ hb,
                                               float* __restrict__ als,
                                               float* __restrict__ ald,
                                               int N) {
    constexpr int K = 256;
    constexpr int M = 256;
    __shared__ unsigned short Ah[64][36];
    __shared__ unsigned short Bh[256][36], Bl[256][36];
    const int tid = threadIdx.x;
    const int lane = tid & 63;
    const int wid = tid >> 6;
    const int row0 = blockIdx.x * 64;

    const int sr = tid >> 2;
    const int sk = (tid & 3) << 3;
    const int ga = row0 + sr;
    const size_t gaK = (size_t)ga * K;

    const int wc0 = wid * 64;
    const int fr = lane & 15;
    const int ko = (lane >> 4) * 8;

    f32x4 acc[4][4];
#pragma unroll
    for (int i = 0; i < 4; ++i)
#pragma unroll
        for (int j = 0; j < 4; ++j) acc[i][j] = (f32x4){0.f, 0.f, 0.f, 0.f};

    for (int k0 = 0; k0 < K; k0 += 32) {
        ushort8 ah = {0,0,0,0,0,0,0,0};
        if (ga < N) ah = *reinterpret_cast<const ushort8*>(&Ab[gaK + k0 + sk]);
        *reinterpret_cast<ushort8*>(&Ah[sr][sk]) = ah;
#pragma unroll
        for (int p = 0; p < 4; ++p) {
            const int m = sr + 64 * p;
            const size_t gm = (size_t)m * K + k0 + sk;
            *reinterpret_cast<ushort8*>(&Bh[m][sk]) =
                *reinterpret_cast<const ushort8*>(&Whi[gm]);
            *reinterpret_cast<ushort8*>(&Bl[m][sk]) =
                *reinterpret_cast<const ushort8*>(&Wlo[gm]);
        }
        __syncthreads();

        bf16x8 av[4];
#pragma unroll
        for (int i = 0; i < 4; ++i)
            av[i] = *reinterpret_cast<const bf16x8*>(&Ah[i * 16 + fr][ko]);
#pragma unroll
        for (int j = 0; j < 4; ++j) {
            const bf16x8 bh = *reinterpret_cast<const bf16x8*>(&Bh[wc0 + j * 16 + fr][ko]);
            const bf16x8 bl = *reinterpret_cast<const bf16x8*>(&Bl[wc0 + j * 16 + fr][ko]);
#pragma unroll
            for (int i = 0; i < 4; ++i) {
                acc[i][j] = __builtin_amdgcn_mfma_f32_16x16x32_bf16(av[i], bh, acc[i][j], 0, 0, 0);
                acc[i][j] = __builtin_amdgcn_mfma_f32_16x16x32_bf16(av[i], bl, acc[i][j], 0, 0, 0);
            }
        }
        __syncthreads();
    }

    const int orow = (lane >> 4) * 4;
    const int ocol = lane & 15;

#pragma unroll
    for (int i = 0; i < 4; ++i) {
#pragma unroll
        for (int r = 0; r < 4; ++r) {
            const int row = row0 + i * 16 + orow + r;
            if (row < N) {
#pragma unroll
                for (int j = 0; j < 4; ++j) {
                    const int col = wc0 + j * 16 + ocol;
                    hb[(size_t)row * M + col] = f2bf_rne(acc[i][j][r]);
                }
            }
        }
    }

    const float as0 = asrc[wc0 + ocol],      as1 = asrc[wc0 + 16 + ocol];
    const float as2 = asrc[wc0 + 32 + ocol], as3 = asrc[wc0 + 48 + ocol];
    const float ad0 = adst[wc0 + ocol],      ad1 = adst[wc0 + 16 + ocol];
    const float ad2 = adst[wc0 + 32 + ocol], ad3 = adst[wc0 + 48 + ocol];
    const int headA = wc0 >> 5, headB = headA + 1;

#pragma unroll
    for (int i = 0; i < 4; ++i) {
#pragma unroll
        for (int r = 0; r < 4; ++r) {
            float psA = acc[i][0][r] * as0 + acc[i][1][r] * as1;
            float pdA = acc[i][0][r] * ad0 + acc[i][1][r] * ad1;
            float psB = acc[i][2][r] * as2 + acc[i][3][r] * as3;
            float pdB = acc[i][2][r] * ad2 + acc[i][3][r] * ad3;
#pragma unroll
            for (int o = 1; o < 16; o <<= 1) {
                psA += __shfl_xor(psA, o);
                pdA += __shfl_xor(pdA, o);
                psB += __shfl_xor(psB, o);
                pdB += __shfl_xor(pdB, o);
            }
            const int row = row0 + i * 16 + orow + r;
            if (ocol == 0 && row < N) {
                als[(size_t)row * 8 + headA] = psA;
                ald[(size_t)row * 8 + headA] = pdA;
                als[(size_t)row * 8 + headB] = psB;
                ald[(size_t)row * 8 + headB] = pdB;
            }
        }
    }
}

// ---------------- layer-3 GEMM (M=64): A bf16, W split, 2 MFMA/frag ---------

__global__ __launch_bounds__(256) void k_gemm_s(const unsigned short* __restrict__ Ab,
                                                const unsigned short* __restrict__ Whi,
                                                const unsigned short* __restrict__ Wlo,
                                                const float* __restrict__ asrc,
                                                const float* __restrict__ adst,
                                                unsigned short* __restrict__ hb,
                                                float* __restrict__ als,
                                                float* __restrict__ ald,
                                                int N) {
    constexpr int K = 256;
    constexpr int M = 64;
    __shared__ unsigned short Ah[64][40], Bh[64][40], Bl[64][40];
    const int tid = threadIdx.x;
    const int lane = tid & 63;
    const int wid = tid >> 6;
    const int row0 = blockIdx.x * 64;

    const int sr = tid >> 2;
    const int sk = (tid & 3) << 3;
    const int ga = row0 + sr;
    const size_t gaK = (size_t)ga * K;
    const size_t gcK = (size_t)sr * K;   // col0 = 0 (M=64)

    const int wr = (wid >> 1) * 32;
    const int wc = (wid & 1) * 32;
    const int fr = lane & 15;
    const int ko = (lane >> 4) * 8;

    f32x4 acc[2][2];
#pragma unroll
    for (int i = 0; i < 2; ++i)
#pragma unroll
        for (int j = 0; j < 2; ++j) acc[i][j] = (f32x4){0.f, 0.f, 0.f, 0.f};

    for (int k0 = 0; k0 < K; k0 += 32) {
        ushort8 ah = {0,0,0,0,0,0,0,0};
        if (ga < N) ah = *reinterpret_cast<const ushort8*>(&Ab[gaK + k0 + sk]);
        const ushort8 bh = *reinterpret_cast<const ushort8*>(&Whi[gcK + k0 + sk]);
        const ushort8 bl = *reinterpret_cast<const ushort8*>(&Wlo[gcK + k0 + sk]);
        *reinterpret_cast<ushort8*>(&Ah[sr][sk]) = ah;
        *reinterpret_cast<ushort8*>(&Bh[sr][sk]) = bh;
        *reinterpret_cast<ushort8*>(&Bl[sr][sk]) = bl;
        __syncthreads();

        bf16x8 av[2], bhv[2], blv[2];
#pragma unroll
        for (int i = 0; i < 2; ++i)
            av[i] = *reinterpret_cast<const bf16x8*>(&Ah[wr + i * 16 + fr][ko]);
#pragma unroll
        for (int j = 0; j < 2; ++j) {
            bhv[j] = *reinterpret_cast<const bf16x8*>(&Bh[wc + j * 16 + fr][ko]);
            blv[j] = *reinterpret_cast<const bf16x8*>(&Bl[wc + j * 16 + fr][ko]);
        }
#pragma unroll
        for (int i = 0; i < 2; ++i)
#pragma unroll
            for (int j = 0; j < 2; ++j) {
                acc[i][j] = __builtin_amdgcn_mfma_f32_16x16x32_bf16(av[i], bhv[j], acc[i][j], 0, 0, 0);
                acc[i][j] = __builtin_amdgcn_mfma_f32_16x16x32_bf16(av[i], blv[j], acc[i][j], 0, 0, 0);
            }
        __syncthreads();
    }

    const int orow = (lane >> 4) * 4;
    const int ocol = lane & 15;

#pragma unroll
    for (int i = 0; i < 2; ++i) {
#pragma unroll
        for (int r = 0; r < 4; ++r) {
            const int row = row0 + wr + i * 16 + orow + r;
            if (row < N) {
#pragma unroll
                for (int j = 0; j < 2; ++j) {
                    const int col = wc + j * 16 + ocol;
                    hb[(size_t)row * M + col] = f2bf_rne(acc[i][j][r]);
                }
            }
        }
    }

    const float as0 = asrc[wc + ocol],      as1 = asrc[wc + 16 + ocol];
    const float ad0 = adst[wc + ocol],      ad1 = adst[wc + 16 + ocol];

    {
        __shared__ float part[2][64][2];
#pragma unroll
        for (int i = 0; i < 2; ++i) {
#pragma unroll
            for (int r = 0; r < 4; ++r) {
                float ps = acc[i][0][r] * as0 + acc[i][1][r] * as1;
                float pd = acc[i][0][r] * ad0 + acc[i][1][r] * ad1;
#pragma unroll
                for (int o = 1; o < 16; o <<= 1) {
                    ps += __shfl_xor(ps, o);
                    pd += __shfl_xor(pd, o);
                }
                if (ocol == 0) {
                    const int lr = wr + i * 16 + orow + r;
                    part[wc >> 5][lr][0] = ps;
                    part[wc >> 5][lr][1] = pd;
                }
            }
        }
        __syncthreads();
        if (tid < 64) {
            const int row = row0 + tid;
            if (row < N) {
                als[row] = part[0][tid][0] + part[1][tid][0];
                ald[row] = part[0][tid][1] + part[1][tid][1];
            }
        }
    }
}

// ---------------- big-layer softmax + aggregate; bf16 out (RNE) -------------
template <int HN, int CN, int VEC, int P, bool OBF>
__global__ __launch_bounds__(256) void k_agg6(const unsigned short* __restrict__ hb,
                                              const float* __restrict__ als,
                                              const float* __restrict__ ald,
                                              const int* __restrict__ ptr,
                                              const int* __restrict__ srcs,
                                              const float* __restrict__ bias,
                                              unsigned short* __restrict__ obf,
                                              float* __restrict__ out,
                                              int N, int relu) {
    constexpr int HC = HN * CN;
    constexpr int SUBS = 64 / HN;
    constexpr int GB = (SUBS < 16) ? SUBS : 16;
    const int l = threadIdx.x & 63;
    const int n = blockIdx.x * 4 + (threadIdx.x >> 6);
    if (n >= N) return;
    const int beg = ptr[n], end = ptr[n + 1];
    const int hd_e = l % HN;
    const int sub = l / HN;
    const float aldv = ald[(unsigned)n * HN + hd_e];

    float p[P];
    int   sr[P];
    float ssum = 0.f;
#pragma unroll
    for (int b = 0; b < P; ++b) {
        const int j = beg + b * SUBS + sub;
        float pv = 0.f; int s = 0;
        if (j < end) {
            s = srcs[j];
            pv = __expf(leaky(als[(unsigned)s * HN + hd_e] + aldv));
        }
        sr[b] = s; p[b] = pv; ssum += pv;
    }
    for (int j = beg + P * SUBS + sub; j < end; j += SUBS) {
        ssum += __expf(leaky(als[(unsigned)srcs[j] * HN + hd_e] + aldv));
    }
#pragma unroll
    for (int o = HN; o < 64; o <<= 1) ssum += __shfl_xor(ssum, o);
    const float inv = 1.f / (ssum + 1e-16f);

    const int ch = l * VEC;
    const int hl = ch / CN;
    float acc[VEC];
#pragma unroll
    for (int v = 0; v < VEC; ++v) acc[v] = 0.f;

#pragma unroll
    for (int b = 0; b < P; ++b) {
        const int j0 = beg + b * SUBS;
        if (j0 >= end) break;
        const float am = p[b] * inv;
#pragma unroll
        for (int cb = 0; cb < SUBS / GB; ++cb) {
            if (j0 + cb * GB >= end) break;
            float av[GB];
            ushort4 hv[GB];
#pragma unroll
            for (int c = 0; c < GB; ++c) {
                const int ce = cb * GB + c;
                const int s = __shfl(sr[b], ce * HN);
                av[c] = __shfl(am, ce * HN + hl);
                hv[c] = *reinterpret_cast<const ushort4*>(&hb[(unsigned)s * HC + ch]);
            }
#pragma unroll
            for (int c = 0; c < GB; ++c) {
                acc[0] += av[c] * bfu(hv[c].x);
                acc[1] += av[c] * bfu(hv[c].y);
                acc[2] += av[c] * bfu(hv[c].z);
                acc[3] += av[c] * bfu(hv[c].w);
            }
        }
    }
    for (int j0 = beg + P * SUBS; j0 < end; j0 += SUBS) {
        const int j = j0 + sub;
        int sm = 0; float am = 0.f;
        if (j < end) {
            sm = srcs[j];
            am = __expf(leaky(als[(unsigned)sm * HN + hd_e] + aldv)) * inv;
        }
#pragma unroll
        for (int cb = 0; cb < SUBS / GB; ++cb) {
            if (j0 + cb * GB >= end) break;
            float av[GB];
            ushort4 hv[GB];
#pragma unroll
            for (int c = 0; c < GB; ++c) {
                const int ce = cb * GB + c;
                const int s = __shfl(sm, ce * HN);
                av[c] = __shfl(am, ce * HN + hl);
                hv[c] = *reinterpret_cast<const ushort4*>(&hb[(unsigned)s * HC + ch]);
            }
#pragma unroll
            for (int c = 0; c < GB; ++c) {
                acc[0] += av[c] * bfu(hv[c].x);
                acc[1] += av[c] * bfu(hv[c].y);
                acc[2] += av[c] * bfu(hv[c].z);
                acc[3] += av[c] * bfu(hv[c].w);
            }
        }
    }

#pragma unroll
    for (int v = 0; v < VEC; ++v) {
        float o = acc[v] + bias[ch + v];
        if (relu) o = fmaxf(o, 0.f);
        acc[v] = o;
    }
    if constexpr (OBF) {
        ushort4 ho;
        ho.x = f2bf_rne(acc[0]);
        ho.y = f2bf_rne(acc[1]);
        ho.z = f2bf_rne(acc[2]);
        ho.w = f2bf_rne(acc[3]);
        *reinterpret_cast<ushort4*>(&obf[(unsigned)n * HC + ch]) = ho;
    } else {
        float4 vout;
        vout.x = acc[0]; vout.y = acc[1]; vout.z = acc[2]; vout.w = acc[3];
        *reinterpret_cast<float4*>(&out[(unsigned)n * HC + ch]) = vout;
    }
}

// ---------------- layer-3 aggregate (round-12 verbatim, passing) ------------
template <int P>
__global__ __launch_bounds__(256) void k_agg7(const unsigned short* __restrict__ hb,
                                              const float* __restrict__ als,
                                              const float* __restrict__ ald,
                                              const int* __restrict__ ptr,
                                              const int* __restrict__ srcs,
                                              const float* __restrict__ bias,
                                              float* __restrict__ out,
                                              int N) {
    constexpr int HC = 64;
    const int l = threadIdx.x & 63;
    const int n = blockIdx.x * 4 + (threadIdx.x >> 6);
    if (n >= N) return;
    const int beg = ptr[n], end = ptr[n + 1];
    const float aldv = ald[n];

    float p[P];
    int   sr[P];
    float ssum = 0.f;
#pragma unroll
    for (int b = 0; b < P; ++b) {
        const int j = beg + b * 64 + l;
        float pv = 0.f; int s = 0;
        if (j < end) { s = srcs[j]; pv = __expf(leaky(als[s] + aldv)); }
        sr[b] = s; p[b] = pv; ssum += pv;
    }
    for (int j = beg + P * 64 + l; j < end; j += 64)
        ssum += __expf(leaky(als[srcs[j]] + aldv));
#pragma unroll
    for (int o = 1; o < 64; o <<= 1) ssum += __shfl_xor(ssum, o);
    const float inv = 1.f / (ssum + 1e-16f);

    const int grp = l >> 4;
    const int lch = (l & 15) * 4;
    float acc[4] = {0.f, 0.f, 0.f, 0.f};

#pragma unroll
    for (int b = 0; b < P; ++b) {
        const int j0 = beg + b * 64;
        if (j0 >= end) break;
        const float am = p[b] * inv;
        const int ned = min(64, end - j0);
        const int nblk = (ned + 15) >> 4;
        for (int cb = 0; cb < nblk; ++cb) {
            const int e0 = cb * 16 + grp;
            const float a0 = __shfl(am, e0),       a1 = __shfl(am, e0 + 4);
            const float a2 = __shfl(am, e0 + 8),   a3 = __shfl(am, e0 + 12);
            const int   s0 = __shfl(sr[b], e0),      s1 = __shfl(sr[b], e0 + 4);
            const int   s2 = __shfl(sr[b], e0 + 8),  s3 = __shfl(sr[b], e0 + 12);
            const ushort4 h0 = *reinterpret_cast<const ushort4*>(&hb[(unsigned)s0 * HC + lch]);
            const ushort4 h1 = *reinterpret_cast<const ushort4*>(&hb[(unsigned)s1 * HC + lch]);
            const ushort4 h2 = *reinterpret_cast<const ushort4*>(&hb[(unsigned)s2 * HC + lch]);
            const ushort4 h3 = *reinterpret_cast<const ushort4*>(&hb[(unsigned)s3 * HC + lch]);
            acc[0] += a0 * bfu(h0.x) + a1 * bfu(h1.x) + a2 * bfu(h2.x) + a3 * bfu(h3.x);
            acc[1] += a0 * bfu(h0.y) + a1 * bfu(h1.y) + a2 * bfu(h2.y) + a3 * bfu(h3.y);
            acc[2] += a0 * bfu(h0.z) + a1 * bfu(h1.z) + a2 * bfu(h2.z) + a3 * bfu(h3.z);
            acc[3] += a0 * bfu(h0.w) + a1 * bfu(h1.w) + a2 * bfu(h2.w) + a3 * bfu(h3.w);
        }
    }
    for (int j0 = beg + P * 64; j0 < end; j0 += 64) {
        const int j = j0 + l;
        int sm = 0; float am = 0.f;
        if (j < end) { sm = srcs[j]; am = __expf(leaky(als[sm] + aldv)) * inv; }
        const int ned = min(64, end - j0);
        const int nblk = (ned + 15) >> 4;
        for (int cb = 0; cb < nblk; ++cb) {
            const int e0 = cb * 16 + grp;
            const float a0 = __shfl(am, e0),       a1 = __shfl(am, e0 + 4);
            const float a2 = __shfl(am, e0 + 8),   a3 = __shfl(am, e0 + 12);
            const int   s0 = __shfl(sm, e0),       s1 = __shfl(sm, e0 + 4);
            const int   s2 = __shfl(sm, e0 + 8),   s3 = __shfl(sm, e0 + 12);
            const ushort4 h0 = *reinterpret_cast<const ushort4*>(&hb[(unsigned)s0 * HC + lch]);
            const ushort4 h1 = *reinterpret_cast<const ushort4*>(&hb[(unsigned)s1 * HC + lch]);
            const ushort4 h2 = *reinterpret_cast<const ushort4*>(&hb[(unsigned)s2 * HC + lch]);
            const ushort4 h3 = *reinterpret_cast<const ushort4*>(&hb[(unsigned)s3 * HC + lch]);
            acc[0] += a0 * bfu(h0.x) + a1 * bfu(h1.x) + a2 * bfu(h2.x) + a3 * bfu(h3.x);
            acc[1] += a0 * bfu(h0.y) + a1 * bfu(h1.y) + a2 * bfu(h2.y) + a3 * bfu(h3.y);
            acc[2] += a0 * bfu(h0.z) + a1 * bfu(h1.z) + a2 * bfu(h2.z) + a3 * bfu(h3.z);
            acc[3] += a0 * bfu(h0.w) + a1 * bfu(h1.w) + a2 * bfu(h2.w) + a3 * bfu(h3.w);
        }
    }

#pragma unroll
    for (int o = 16; o < 64; o <<= 1) {
#pragma unroll
        for (int v = 0; v < 4; ++v) acc[v] += __shfl_xor(acc[v], o);
    }

    if (l < 16) {
        float4 vout;
        vout.x = acc[0] + bias[lch + 0];
        vout.y = acc[1] + bias[lch + 1];
        vout.z = acc[2] + bias[lch + 2];
        vout.w = acc[3] + bias[lch + 3];
        *reinterpret_cast<float4*>(&out[(size_t)n * HC + lch]) = vout;
    }
}

// ---------------- launch ----------------

extern "C" void kernel_launch(void* const* d_in, const int* in_sizes, int n_in,
                              void* d_out, int out_size, void* d_ws, size_t ws_size,
                              hipStream_t stream) {
    const float* x   = (const float*)d_in[0];
    const int*   ei  = (const int*)d_in[1];
    const float* W1  = (const float*)d_in[2];
    const float* as1 = (const float*)d_in[3];
    const float* ad1 = (const float*)d_in[4];
    const float* b1  = (const float*)d_in[5];
    const float* W2  = (const float*)d_in[6];
    const float* as2 = (const float*)d_in[7];
    const float* ad2 = (const float*)d_in[8];
    const float* b2  = (const float*)d_in[9];
    const float* W3  = (const float*)d_in[10];
    const float* as3 = (const float*)d_in[11];
    const float* ad3 = (const float*)d_in[12];
    const float* b3  = (const float*)d_in[13];

    const int F  = 256;
    const int N  = in_sizes[0] / F;     // 50000
    const int E  = in_sizes[1] / 2;     // 800000
    const int Et = E + N;

    char* w = (char*)d_ws;
    auto alloc = [&](size_t bytes) {
        char* p = w;
        w += (bytes + 255) & ~(size_t)255;
        return p;
    };
    unsigned short* xb   = (unsigned short*)alloc((size_t)N * F * 2);  // x / act2 (bf16)
    unsigned short* act1 = (unsigned short*)alloc((size_t)N * F * 2);  // act1 (bf16)
    unsigned short* hB   = (unsigned short*)alloc((size_t)N * F * 2);  // gemm out (bf16)
    unsigned short* Wt1hi = (unsigned short*)alloc((size_t)256 * 256 * 2);
    unsigned short* Wt1lo = (unsigned short*)alloc((size_t)256 * 256 * 2);
    unsigned short* Wt2hi = (unsigned short*)alloc((size_t)256 * 256 * 2);
    unsigned short* Wt2lo = (unsigned short*)alloc((size_t)256 * 256 * 2);
    unsigned short* Wt3hi = (unsigned short*)alloc((size_t)64 * 256 * 2);
    unsigned short* Wt3lo = (unsigned short*)alloc((size_t)64 * 256 * 2);
    float* als  = (float*)alloc((size_t)N * 8 * 4);
    float* ald  = (float*)alloc((size_t)N * 8 * 4);
    int*   cnt  = (int*)alloc((size_t)N * 4);
    int*   ptr  = (int*)alloc((size_t)(N + 1) * 4);
    int*   fptr = (int*)alloc((size_t)(N + 1) * 4);
    int*   srcs = (int*)alloc((size_t)Et * 4);
    int*   bsum = (int*)alloc(4096);

    const int n8 = N * F / 8;
    const int nsplit = (n8 + 255) / 256;
    const int nprep = nsplit + 64 + 64 + 16;

    hipMemsetAsync(cnt, 0, (size_t)N * 4, stream);
    hipLaunchKernelGGL(k_prep, dim3(nprep), dim3(256), 0, stream,
                       x, xb, n8,
                       W1, Wt1hi, Wt1lo, W2, Wt2hi, Wt2lo, W3, Wt3hi, Wt3lo,
                       nsplit);

    const int nb = (N + 1023) / 1024;
    hipLaunchKernelGGL(k_count,     dim3((E + 255) / 256),  dim3(256), 0, stream, ei + E, cnt, E);
    hipLaunchKernelGGL(k_scan_local,dim3(nb),               dim3(256), 0, stream, cnt, ptr, bsum, N);
    hipLaunchKernelGGL(k_scan_add2, dim3((N + 256) / 256),  dim3(256), 0, stream, ptr, fptr, bsum, N, Et);
    hipLaunchKernelGGL(k_fillcsr,   dim3((Et + 255) / 256), dim3(256), 0, stream, ei, fptr, srcs, E, Et);

    const dim3 gN4((N + 3) / 4);
    const int gx = (N + 63) / 64;

    // ---- layer 1 ----
    hipLaunchKernelGGL(k_gemm2, dim3(gx), dim3(256), 0, stream,
                       xb, Wt1hi, Wt1lo, as1, ad1, hB, als, ald, N);
    hipLaunchKernelGGL((k_agg6<8, 32, 4, 8, true>), gN4, dim3(256), 0, stream,
                       hB, als, ald, ptr, srcs, b1, act1, nullptr, N, 1);
    // ---- layer 2 ----
    hipLaunchKernelGGL(k_gemm2, dim3(gx), dim3(256), 0, stream,
                       act1, Wt2hi, Wt2lo, as2, ad2, hB, als, ald, N);
    hipLaunchKernelGGL((k_agg6<8, 32, 4, 8, true>), gN4, dim3(256), 0, stream,
                       hB, als, ald, ptr, srcs, b2, xb, nullptr, N, 1);
    // ---- layer 3 ----
    hipLaunchKernelGGL(k_gemm_s, dim3(gx), dim3(256), 0, stream,
                       xb, Wt3hi, Wt3lo, as3, ad3, hB, als, ald, N);
    hipLaunchKernelGGL((k_agg7<2>), gN4, dim3(256), 0, stream,
                       hB, als, ald, ptr, srcs, b3, (float*)d_out, N);
}

// Round 17
// 350.718 us; speedup vs baseline: 1.1498x; 1.0481x over previous
//
#include <hip/hip_runtime.h>
#include <math.h>

#define NSLOPE 0.2f

typedef __attribute__((ext_vector_type(8))) short bf16x8;
typedef __attribute__((ext_vector_type(8))) unsigned short ushort8;
typedef __attribute__((ext_vector_type(4))) float f32x4;

static __device__ __forceinline__ float leaky(float e) {
    return e > 0.f ? e : NSLOPE * e;
}

static __device__ __forceinline__ float bfu(unsigned short u) {
    return __uint_as_float(((unsigned)u) << 16);
}

static __device__ __forceinline__ unsigned short f2bf_rne(float f) {
    unsigned b = __float_as_uint(f);
    unsigned r = b + 0x7fffu + ((b >> 16) & 1u);
    return (unsigned short)(r >> 16);
}

// ---------------- CSR build ----------------

__global__ void k_count(const int* __restrict__ dst, int* __restrict__ cnt, int E) {
    int i = blockIdx.x * blockDim.x + threadIdx.x;
    if (i < E) atomicAdd(&cnt[dst[i]], 1);
}

// self-loop +1 folded in
__global__ void k_scan_local(const int* __restrict__ cnt, int* __restrict__ ptr,
                             int* __restrict__ bsum, int N) {
    __shared__ int sd[256];
    int t = threadIdx.x;
    int i0 = blockIdx.x * 1024 + t * 4;
    int v0 = (i0 + 0 < N) ? cnt[i0 + 0] + 1 : 0;
    int v1 = (i0 + 1 < N) ? cnt[i0 + 1] + 1 : 0;
    int v2 = (i0 + 2 < N) ? cnt[i0 + 2] + 1 : 0;
    int v3 = (i0 + 3 < N) ? cnt[i0 + 3] + 1 : 0;
    int ts = v0 + v1 + v2 + v3;
    sd[t] = ts;
    __syncthreads();
    for (int o = 1; o < 256; o <<= 1) {
        int add = (t >= o) ? sd[t - o] : 0;
        __syncthreads();
        sd[t] += add;
        __syncthreads();
    }
    int run = sd[t] - ts;
    if (i0 + 0 < N) ptr[i0 + 0] = run; run += v0;
    if (i0 + 1 < N) ptr[i0 + 1] = run; run += v1;
    if (i0 + 2 < N) ptr[i0 + 2] = run; run += v2;
    if (i0 + 3 < N) ptr[i0 + 3] = run;
    if (t == 255) bsum[blockIdx.x] = sd[255];
}

__global__ void k_scan_add2(int* __restrict__ ptr, int* __restrict__ fptr,
                            const int* __restrict__ bsum, int N, int Et) {
    __shared__ int base;
    const int chunk = blockIdx.x >> 2;
    if (threadIdx.x == 0) {
        int s = 0;
        for (int b = 0; b < chunk; ++b) s += bsum[b];
        base = s;
    }
    __syncthreads();
    int i = blockIdx.x * 256 + threadIdx.x;
    if (i < N) {
        int v = ptr[i] + base;
        ptr[i] = v;
        fptr[i] = v;
    } else if (i == N) {
        ptr[N] = Et;
    }
}

__global__ void k_fillcsr(const int* __restrict__ ei, int* __restrict__ fptr,
                          int* __restrict__ srcs, int E, int Et) {
    int i = blockIdx.x * blockDim.x + threadIdx.x;
    if (i >= Et) return;
    int s, d;
    if (i < E) { s = ei[i]; d = ei[E + i]; }
    else       { s = d = i - E; }
    int pos = atomicAdd(&fptr[d], 1);
    srcs[pos] = s;
}

// ---------------- fused prep: x -> bf16 (RNE)  ||  3x W transpose -> bf16 ---
__global__ __launch_bounds__(256) void k_prep(
    const float* __restrict__ x, unsigned short* __restrict__ xb, int n8,
    const float* __restrict__ W1, unsigned short* __restrict__ w1b,
    const float* __restrict__ W2, unsigned short* __restrict__ w2b,
    const float* __restrict__ W3, unsigned short* __restrict__ w3b,
    int nsplit) {
    __shared__ float tile[32][33];
    const int b = blockIdx.x;
    const int tid = threadIdx.x;
    if (b < nsplit) {
        int i = b * 256 + tid;
        if (i < n8) {
            const float4 v0 = *reinterpret_cast<const float4*>(&x[(size_t)i * 8]);
            const float4 v1 = *reinterpret_cast<const float4*>(&x[(size_t)i * 8 + 4]);
            const float f[8] = {v0.x, v0.y, v0.z, v0.w, v1.x, v1.y, v1.z, v1.w};
            ushort8 h;
#pragma unroll
            for (int j = 0; j < 8; ++j) h[j] = f2bf_rne(f[j]);
            *reinterpret_cast<ushort8*>(&xb[(size_t)i * 8]) = h;
        }
    } else {
        int tb = b - nsplit;            // 0..143
        const float* B; unsigned short* H;
        int M, bx, by;
        if (tb < 64)       { B = W1; H = w1b; M = 256; bx = (tb & 7) * 32; by = (tb >> 3) * 32; }
        else if (tb < 128) { tb -= 64;  B = W2; H = w2b; M = 256; bx = (tb & 7) * 32; by = (tb >> 3) * 32; }
        else               { tb -= 128; B = W3; H = w3b; M = 64;  bx = (tb & 1) * 32; by = (tb >> 1) * 32; }
        constexpr int K = 256;
        const int tx = tid & 31, ty = tid >> 5;
        for (int r = ty; r < 32; r += 8) tile[r][tx] = B[(size_t)(by + r) * M + bx + tx];
        __syncthreads();
        for (int r = ty; r < 32; r += 8)
            H[(size_t)(bx + r) * K + by + tx] = f2bf_rne(tile[tx][r]);
    }
}

// ---------------- wide GEMM, layers 1-2: all-bf16, 1 MFMA/frag --------------
__global__ __launch_bounds__(256) void k_gemm2(const unsigned short* __restrict__ Ab,
                                               const unsigned short* __restrict__ Wb,
                                               const float* __restrict__ asrc,
                                               const float* __restrict__ adst,
                                               unsigned short* __restrict__ hb,
                                               float* __restrict__ als,
                                               float* __restrict__ ald,
                                               int N) {
    constexpr int K = 256;
    constexpr int M = 256;
    __shared__ unsigned short Ah[64][36];
    __shared__ unsigned short Bh[256][36];
    const int tid = threadIdx.x;
    const int lane = tid & 63;
    const int wid = tid >> 6;
    const int row0 = blockIdx.x * 64;

    const int sr = tid >> 2;
    const int sk = (tid & 3) << 3;
    const int ga = row0 + sr;
    const size_t gaK = (size_t)ga * K;

    const int wc0 = wid * 64;
    const int fr = lane & 15;
    const int ko = (lane >> 4) * 8;

    f32x4 acc[4][4];
#pragma unroll
    for (int i = 0; i < 4; ++i)
#pragma unroll
        for (int j = 0; j < 4; ++j) acc[i][j] = (f32x4){0.f, 0.f, 0.f, 0.f};

    for (int k0 = 0; k0 < K; k0 += 32) {
        ushort8 ah = {0,0,0,0,0,0,0,0};
        if (ga < N) ah = *reinterpret_cast<const ushort8*>(&Ab[gaK + k0 + sk]);
        *reinterpret_cast<ushort8*>(&Ah[sr][sk]) = ah;
#pragma unroll
        for (int p = 0; p < 4; ++p) {
            const int m = sr + 64 * p;
            *reinterpret_cast<ushort8*>(&Bh[m][sk]) =
                *reinterpret_cast<const ushort8*>(&Wb[(size_t)m * K + k0 + sk]);
        }
        __syncthreads();

        bf16x8 av[4];
#pragma unroll
        for (int i = 0; i < 4; ++i)
            av[i] = *reinterpret_cast<const bf16x8*>(&Ah[i * 16 + fr][ko]);
#pragma unroll
        for (int j = 0; j < 4; ++j) {
            const bf16x8 bh = *reinterpret_cast<const bf16x8*>(&Bh[wc0 + j * 16 + fr][ko]);
#pragma unroll
            for (int i = 0; i < 4; ++i)
                acc[i][j] = __builtin_amdgcn_mfma_f32_16x16x32_bf16(av[i], bh, acc[i][j], 0, 0, 0);
        }
        __syncthreads();
    }

    const int orow = (lane >> 4) * 4;
    const int ocol = lane & 15;

#pragma unroll
    for (int i = 0; i < 4; ++i) {
#pragma unroll
        for (int r = 0; r < 4; ++r) {
            const int row = row0 + i * 16 + orow + r;
            if (row < N) {
#pragma unroll
                for (int j = 0; j < 4; ++j) {
                    const int col = wc0 + j * 16 + ocol;
                    hb[(size_t)row * M + col] = f2bf_rne(acc[i][j][r]);
                }
            }
        }
    }

    const float as0 = asrc[wc0 + ocol],      as1 = asrc[wc0 + 16 + ocol];
    const float as2 = asrc[wc0 + 32 + ocol], as3 = asrc[wc0 + 48 + ocol];
    const float ad0 = adst[wc0 + ocol],      ad1 = adst[wc0 + 16 + ocol];
    const float ad2 = adst[wc0 + 32 + ocol], ad3 = adst[wc0 + 48 + ocol];
    const int headA = wc0 >> 5, headB = headA + 1;

#pragma unroll
    for (int i = 0; i < 4; ++i) {
#pragma unroll
        for (int r = 0; r < 4; ++r) {
            float psA = acc[i][0][r] * as0 + acc[i][1][r] * as1;
            float pdA = acc[i][0][r] * ad0 + acc[i][1][r] * ad1;
            float psB = acc[i][2][r] * as2 + acc[i][3][r] * as3;
            float pdB = acc[i][2][r] * ad2 + acc[i][3][r] * ad3;
#pragma unroll
            for (int o = 1; o < 16; o <<= 1) {
                psA += __shfl_xor(psA, o);
                pdA += __shfl_xor(pdA, o);
                psB += __shfl_xor(psB, o);
                pdB += __shfl_xor(pdB, o);
            }
            const int row = row0 + i * 16 + orow + r;
            if (ocol == 0 && row < N) {
                als[(size_t)row * 8 + headA] = psA;
                ald[(size_t)row * 8 + headA] = pdA;
                als[(size_t)row * 8 + headB] = psB;
                ald[(size_t)row * 8 + headB] = pdB;
            }
        }
    }
}

// ---------------- layer-3 GEMM (M=64): all-bf16, 1 MFMA/frag ----------------

__global__ __launch_bounds__(256) void k_gemm_s(const unsigned short* __restrict__ Ab,
                                                const unsigned short* __restrict__ Wb,
                                                const float* __restrict__ asrc,
                                                const float* __restrict__ adst,
                                                unsigned short* __restrict__ hb,
                                                float* __restrict__ als,
                                                float* __restrict__ ald,
                                                int N) {
    constexpr int K = 256;
    constexpr int M = 64;
    __shared__ unsigned short Ah[64][40], Bh[64][40];
    const int tid = threadIdx.x;
    const int lane = tid & 63;
    const int wid = tid >> 6;
    const int row0 = blockIdx.x * 64;

    const int sr = tid >> 2;
    const int sk = (tid & 3) << 3;
    const int ga = row0 + sr;
    const size_t gaK = (size_t)ga * K;
    const size_t gcK = (size_t)sr * K;

    const int wr = (wid >> 1) * 32;
    const int wc = (wid & 1) * 32;
    const int fr = lane & 15;
    const int ko = (lane >> 4) * 8;

    f32x4 acc[2][2];
#pragma unroll
    for (int i = 0; i < 2; ++i)
#pragma unroll
        for (int j = 0; j < 2; ++j) acc[i][j] = (f32x4){0.f, 0.f, 0.f, 0.f};

    for (int k0 = 0; k0 < K; k0 += 32) {
        ushort8 ah = {0,0,0,0,0,0,0,0};
        if (ga < N) ah = *reinterpret_cast<const ushort8*>(&Ab[gaK + k0 + sk]);
        const ushort8 bh = *reinterpret_cast<const ushort8*>(&Wb[gcK + k0 + sk]);
        *reinterpret_cast<ushort8*>(&Ah[sr][sk]) = ah;
        *reinterpret_cast<ushort8*>(&Bh[sr][sk]) = bh;
        __syncthreads();

        bf16x8 av[2], bv[2];
#pragma unroll
        for (int i = 0; i < 2; ++i)
            av[i] = *reinterpret_cast<const bf16x8*>(&Ah[wr + i * 16 + fr][ko]);
#pragma unroll
        for (int j = 0; j < 2; ++j)
            bv[j] = *reinterpret_cast<const bf16x8*>(&Bh[wc + j * 16 + fr][ko]);
#pragma unroll
        for (int i = 0; i < 2; ++i)
#pragma unroll
            for (int j = 0; j < 2; ++j)
                acc[i][j] = __builtin_amdgcn_mfma_f32_16x16x32_bf16(av[i], bv[j], acc[i][j], 0, 0, 0);
        __syncthreads();
    }

    const int orow = (lane >> 4) * 4;
    const int ocol = lane & 15;

#pragma unroll
    for (int i = 0; i < 2; ++i) {
#pragma unroll
        for (int r = 0; r < 4; ++r) {
            const int row = row0 + wr + i * 16 + orow + r;
            if (row < N) {
#pragma unroll
                for (int j = 0; j < 2; ++j) {
                    const int col = wc + j * 16 + ocol;
                    hb[(size_t)row * M + col] = f2bf_rne(acc[i][j][r]);
                }
            }
        }
    }

    const float as0 = asrc[wc + ocol],      as1 = asrc[wc + 16 + ocol];
    const float ad0 = adst[wc + ocol],      ad1 = adst[wc + 16 + ocol];

    {
        __shared__ float part[2][64][2];
#pragma unroll
        for (int i = 0; i < 2; ++i) {
#pragma unroll
            for (int r = 0; r < 4; ++r) {
                float ps = acc[i][0][r] * as0 + acc[i][1][r] * as1;
                float pd = acc[i][0][r] * ad0 + acc[i][1][r] * ad1;
#pragma unroll
                for (int o = 1; o < 16; o <<= 1) {
                    ps += __shfl_xor(ps, o);
                    pd += __shfl_xor(pd, o);
                }
                if (ocol == 0) {
                    const int lr = wr + i * 16 + orow + r;
                    part[wc >> 5][lr][0] = ps;
                    part[wc >> 5][lr][1] = pd;
                }
            }
        }
        __syncthreads();
        if (tid < 64) {
            const int row = row0 + tid;
            if (row < N) {
                als[row] = part[0][tid][0] + part[1][tid][0];
                ald[row] = part[0][tid][1] + part[1][tid][1];
            }
        }
    }
}

// ---------------- big-layer softmax + aggregate; bf16 out (RNE) -------------
template <int HN, int CN, int VEC, int P, bool OBF>
__global__ __launch_bounds__(256) void k_agg6(const unsigned short* __restrict__ hb,
                                              const float* __restrict__ als,
                                              const float* __restrict__ ald,
                                              const int* __restrict__ ptr,
                                              const int* __restrict__ srcs,
                                              const float* __restrict__ bias,
                                              unsigned short* __restrict__ obf,
                                              float* __restrict__ out,
                                              int N, int relu) {
    constexpr int HC = HN * CN;
    constexpr int SUBS = 64 / HN;
    constexpr int GB = (SUBS < 16) ? SUBS : 16;
    const int l = threadIdx.x & 63;
    const int n = blockIdx.x * 4 + (threadIdx.x >> 6);
    if (n >= N) return;
    const int beg = ptr[n], end = ptr[n + 1];
    const int hd_e = l % HN;
    const int sub = l / HN;
    const float aldv = ald[(unsigned)n * HN + hd_e];

    float p[P];
    int   sr[P];
    float ssum = 0.f;
#pragma unroll
    for (int b = 0; b < P; ++b) {
        const int j = beg + b * SUBS + sub;
        float pv = 0.f; int s = 0;
        if (j < end) {
            s = srcs[j];
            pv = __expf(leaky(als[(unsigned)s * HN + hd_e] + aldv));
        }
        sr[b] = s; p[b] = pv; ssum += pv;
    }
    for (int j = beg + P * SUBS + sub; j < end; j += SUBS) {
        ssum += __expf(leaky(als[(unsigned)srcs[j] * HN + hd_e] + aldv));
    }
#pragma unroll
    for (int o = HN; o < 64; o <<= 1) ssum += __shfl_xor(ssum, o);
    const float inv = 1.f / (ssum + 1e-16f);

    const int ch = l * VEC;
    const int hl = ch / CN;
    float acc[VEC];
#pragma unroll
    for (int v = 0; v < VEC; ++v) acc[v] = 0.f;

#pragma unroll
    for (int b = 0; b < P; ++b) {
        const int j0 = beg + b * SUBS;
        if (j0 >= end) break;
        const float am = p[b] * inv;
#pragma unroll
        for (int cb = 0; cb < SUBS / GB; ++cb) {
            if (j0 + cb * GB >= end) break;
            float av[GB];
            ushort4 hv[GB];
#pragma unroll
            for (int c = 0; c < GB; ++c) {
                const int ce = cb * GB + c;
                const int s = __shfl(sr[b], ce * HN);
                av[c] = __shfl(am, ce * HN + hl);
                hv[c] = *reinterpret_cast<const ushort4*>(&hb[(unsigned)s * HC + ch]);
            }
#pragma unroll
            for (int c = 0; c < GB; ++c) {
                acc[0] += av[c] * bfu(hv[c].x);
                acc[1] += av[c] * bfu(hv[c].y);
                acc[2] += av[c] * bfu(hv[c].z);
                acc[3] += av[c] * bfu(hv[c].w);
            }
        }
    }
    for (int j0 = beg + P * SUBS; j0 < end; j0 += SUBS) {
        const int j = j0 + sub;
        int sm = 0; float am = 0.f;
        if (j < end) {
            sm = srcs[j];
            am = __expf(leaky(als[(unsigned)sm * HN + hd_e] + aldv)) * inv;
        }
#pragma unroll
        for (int cb = 0; cb < SUBS / GB; ++cb) {
            if (j0 + cb * GB >= end) break;
            float av[GB];
            ushort4 hv[GB];
#pragma unroll
            for (int c = 0; c < GB; ++c) {
                const int ce = cb * GB + c;
                const int s = __shfl(sm, ce * HN);
                av[c] = __shfl(am, ce * HN + hl);
                hv[c] = *reinterpret_cast<const ushort4*>(&hb[(unsigned)s * HC + ch]);
            }
#pragma unroll
            for (int c = 0; c < GB; ++c) {
                acc[0] += av[c] * bfu(hv[c].x);
                acc[1] += av[c] * bfu(hv[c].y);
                acc[2] += av[c] * bfu(hv[c].z);
                acc[3] += av[c] * bfu(hv[c].w);
            }
        }
    }

#pragma unroll
    for (int v = 0; v < VEC; ++v) {
        float o = acc[v] + bias[ch + v];
        if (relu) o = fmaxf(o, 0.f);
        acc[v] = o;
    }
    if constexpr (OBF) {
        ushort4 ho;
        ho.x = f2bf_rne(acc[0]);
        ho.y = f2bf_rne(acc[1]);
        ho.z = f2bf_rne(acc[2]);
        ho.w = f2bf_rne(acc[3]);
        *reinterpret_cast<ushort4*>(&obf[(unsigned)n * HC + ch]) = ho;
    } else {
        float4 vout;
        vout.x = acc[0]; vout.y = acc[1]; vout.z = acc[2]; vout.w = acc[3];
        *reinterpret_cast<float4*>(&out[(unsigned)n * HC + ch]) = vout;
    }
}

// ---------------- layer-3 aggregate (passing, wave-uniform shfl) ------------
template <int P>
__global__ __launch_bounds__(256) void k_agg7(const unsigned short* __restrict__ hb,
                                              const float* __restrict__ als,
                                              const float* __restrict__ ald,
                                              const int* __restrict__ ptr,
                                              const int* __restrict__ srcs,
                                              const float* __restrict__ bias,
                                              float* __restrict__ out,
                                              int N) {
    constexpr int HC = 64;
    const int l = threadIdx.x & 63;
    const int n = blockIdx.x * 4 + (threadIdx.x >> 6);
    if (n >= N) return;
    const int beg = ptr[n], end = ptr[n + 1];
    const float aldv = ald[n];

    float p[P];
    int   sr[P];
    float ssum = 0.f;
#pragma unroll
    for (int b = 0; b < P; ++b) {
        const int j = beg + b * 64 + l;
        float pv = 0.f; int s = 0;
        if (j < end) { s = srcs[j]; pv = __expf(leaky(als[s] + aldv)); }
        sr[b] = s; p[b] = pv; ssum += pv;
    }
    for (int j = beg + P * 64 + l; j < end; j += 64)
        ssum += __expf(leaky(als[srcs[j]] + aldv));
#pragma unroll
    for (int o = 1; o < 64; o <<= 1) ssum += __shfl_xor(ssum, o);
    const float inv = 1.f / (ssum + 1e-16f);

    const int grp = l >> 4;
    const int lch = (l & 15) * 4;
    float acc[4] = {0.f, 0.f, 0.f, 0.f};

#pragma unroll
    for (int b = 0; b < P; ++b) {
        const int j0 = beg + b * 64;
        if (j0 >= end) break;
        const float am = p[b] * inv;
        const int ned = min(64, end - j0);
        const int nblk = (ned + 15) >> 4;
        for (int cb = 0; cb < nblk; ++cb) {
            const int e0 = cb * 16 + grp;
            const float a0 = __shfl(am, e0),       a1 = __shfl(am, e0 + 4);
            const float a2 = __shfl(am, e0 + 8),   a3 = __shfl(am, e0 + 12);
            const int   s0 = __shfl(sr[b], e0),      s1 = __shfl(sr[b], e0 + 4);
            const int   s2 = __shfl(sr[b], e0 + 8),  s3 = __shfl(sr[b], e0 + 12);
            const ushort4 h0 = *reinterpret_cast<const ushort4*>(&hb[(unsigned)s0 * HC + lch]);
            const ushort4 h1 = *reinterpret_cast<const ushort4*>(&hb[(unsigned)s1 * HC + lch]);
            const ushort4 h2 = *reinterpret_cast<const ushort4*>(&hb[(unsigned)s2 * HC + lch]);
            const ushort4 h3 = *reinterpret_cast<const ushort4*>(&hb[(unsigned)s3 * HC + lch]);
            acc[0] += a0 * bfu(h0.x) + a1 * bfu(h1.x) + a2 * bfu(h2.x) + a3 * bfu(h3.x);
            acc[1] += a0 * bfu(h0.y) + a1 * bfu(h1.y) + a2 * bfu(h2.y) + a3 * bfu(h3.y);
            acc[2] += a0 * bfu(h0.z) + a1 * bfu(h1.z) + a2 * bfu(h2.z) + a3 * bfu(h3.z);
            acc[3] += a0 * bfu(h0.w) + a1 * bfu(h1.w) + a2 * bfu(h2.w) + a3 * bfu(h3.w);
        }
    }
    for (int j0 = beg + P * 64; j0 < end; j0 += 64) {
        const int j = j0 + l;
        int sm = 0; float am = 0.f;
        if (j < end) { sm = srcs[j]; am = __expf(leaky(als[sm] + aldv)) * inv; }
        const int ned = min(64, end - j0);
        const int nblk = (ned + 15) >> 4;
        for (int cb = 0; cb < nblk; ++cb) {
            const int e0 = cb * 16 + grp;
            const float a0 = __shfl(am, e0),       a1 = __shfl(am, e0 + 4);
            const float a2 = __shfl(am, e0 + 8),   a3 = __shfl(am, e0 + 12);
            const int   s0 = __shfl(sm, e0),       s1 = __shfl(sm, e0 + 4);
            const int   s2 = __shfl(sm, e0 + 8),   s3 = __shfl(sm, e0 + 12);
            const ushort4 h0 = *reinterpret_cast<const ushort4*>(&hb[(unsigned)s0 * HC + lch]);
            const ushort4 h1 = *reinterpret_cast<const ushort4*>(&hb[(unsigned)s1 * HC + lch]);
            const ushort4 h2 = *reinterpret_cast<const ushort4*>(&hb[(unsigned)s2 * HC + lch]);
            const ushort4 h3 = *reinterpret_cast<const ushort4*>(&hb[(unsigned)s3 * HC + lch]);
            acc[0] += a0 * bfu(h0.x) + a1 * bfu(h1.x) + a2 * bfu(h2.x) + a3 * bfu(h3.x);
            acc[1] += a0 * bfu(h0.y) + a1 * bfu(h1.y) + a2 * bfu(h2.y) + a3 * bfu(h3.y);
            acc[2] += a0 * bfu(h0.z) + a1 * bfu(h1.z) + a2 * bfu(h2.z) + a3 * bfu(h3.z);
            acc[3] += a0 * bfu(h0.w) + a1 * bfu(h1.w) + a2 * bfu(h2.w) + a3 * bfu(h3.w);
        }
    }

#pragma unroll
    for (int o = 16; o < 64; o <<= 1) {
#pragma unroll
        for (int v = 0; v < 4; ++v) acc[v] += __shfl_xor(acc[v], o);
    }

    if (l < 16) {
        float4 vout;
        vout.x = acc[0] + bias[lch + 0];
        vout.y = acc[1] + bias[lch + 1];
        vout.z = acc[2] + bias[lch + 2];
        vout.w = acc[3] + bias[lch + 3];
        *reinterpret_cast<float4*>(&out[(size_t)n * HC + lch]) = vout;
    }
}

// ---------------- launch ----------------

extern "C" void kernel_launch(void* const* d_in, const int* in_sizes, int n_in,
                              void* d_out, int out_size, void* d_ws, size_t ws_size,
                              hipStream_t stream) {
    const float* x   = (const float*)d_in[0];
    const int*   ei  = (const int*)d_in[1];
    const float* W1  = (const float*)d_in[2];
    const float* as1 = (const float*)d_in[3];
    const float* ad1 = (const float*)d_in[4];
    const float* b1  = (const float*)d_in[5];
    const float* W2  = (const float*)d_in[6];
    const float* as2 = (const float*)d_in[7];
    const float* ad2 = (const float*)d_in[8];
    const float* b2  = (const float*)d_in[9];
    const float* W3  = (const float*)d_in[10];
    const float* as3 = (const float*)d_in[11];
    const float* ad3 = (const float*)d_in[12];
    const float* b3  = (const float*)d_in[13];

    const int F  = 256;
    const int N  = in_sizes[0] / F;     // 50000
    const int E  = in_sizes[1] / 2;     // 800000
    const int Et = E + N;

    char* w = (char*)d_ws;
    auto alloc = [&](size_t bytes) {
        char* p = w;
        w += (bytes + 255) & ~(size_t)255;
        return p;
    };
    unsigned short* xb   = (unsigned short*)alloc((size_t)N * F * 2);  // x / act2 (bf16)
    unsigned short* act1 = (unsigned short*)alloc((size_t)N * F * 2);  // act1 (bf16)
    unsigned short* hB   = (unsigned short*)alloc((size_t)N * F * 2);  // gemm out (bf16)
    unsigned short* Wt1b = (unsigned short*)alloc((size_t)256 * 256 * 2);
    unsigned short* Wt2b = (unsigned short*)alloc((size_t)256 * 256 * 2);
    unsigned short* Wt3b = (unsigned short*)alloc((size_t)64 * 256 * 2);
    float* als  = (float*)alloc((size_t)N * 8 * 4);
    float* ald  = (float*)alloc((size_t)N * 8 * 4);
    int*   cnt  = (int*)alloc((size_t)N * 4);
    int*   ptr  = (int*)alloc((size_t)(N + 1) * 4);
    int*   fptr = (int*)alloc((size_t)(N + 1) * 4);
    int*   srcs = (int*)alloc((size_t)Et * 4);
    int*   bsum = (int*)alloc(4096);

    const int n8 = N * F / 8;
    const int nsplit = (n8 + 255) / 256;
    const int nprep = nsplit + 64 + 64 + 16;

    hipMemsetAsync(cnt, 0, (size_t)N * 4, stream);
    hipLaunchKernelGGL(k_prep, dim3(nprep), dim3(256), 0, stream,
                       x, xb, n8, W1, Wt1b, W2, Wt2b, W3, Wt3b, nsplit);

    const int nb = (N + 1023) / 1024;
    hipLaunchKernelGGL(k_count,     dim3((E + 255) / 256),  dim3(256), 0, stream, ei + E, cnt, E);
    hipLaunchKernelGGL(k_scan_local,dim3(nb),               dim3(256), 0, stream, cnt, ptr, bsum, N);
    hipLaunchKernelGGL(k_scan_add2, dim3((N + 256) / 256),  dim3(256), 0, stream, ptr, fptr, bsum, N, Et);
    hipLaunchKernelGGL(k_fillcsr,   dim3((Et + 255) / 256), dim3(256), 0, stream, ei, fptr, srcs, E, Et);

    const dim3 gN4((N + 3) / 4);
    const int gx = (N + 63) / 64;

    // ---- layer 1 ----
    hipLaunchKernelGGL(k_gemm2, dim3(gx), dim3(256), 0, stream,
                       xb, Wt1b, as1, ad1, hB, als, ald, N);
    hipLaunchKernelGGL((k_agg6<8, 32, 4, 8, true>), gN4, dim3(256), 0, stream,
                       hB, als, ald, ptr, srcs, b1, act1, nullptr, N, 1);
    // ---- layer 2 ----
    hipLaunchKernelGGL(k_gemm2, dim3(gx), dim3(256), 0, stream,
                       act1, Wt2b, as2, ad2, hB, als, ald, N);
    hipLaunchKernelGGL((k_agg6<8, 32, 4, 8, true>), gN4, dim3(256), 0, stream,
                       hB, als, ald, ptr, srcs, b2, xb, nullptr, N, 1);
    // ---- layer 3 ----
    hipLaunchKernelGGL(k_gemm_s, dim3(gx), dim3(256), 0, stream,
                       xb, Wt3b, as3, ad3, hB, als, ald, N);
    hipLaunchKernelGGL((k_agg7<2>), gN4, dim3(256), 0, stream,
                       hB, als, ald, ptr, srcs, b3, (float*)d_out, N);
}